// Round 1
// baseline (587.299 us; speedup 1.0000x reference)
//
#include <hip/hip_runtime.h>
#include <math.h>
#include <stdint.h>

#define NN 50000
#define NE 800000
#define NG 64
#define NEG_SLOPE 0.2f

__device__ __forceinline__ float lrelu(float x) { return x > 0.f ? x : NEG_SLOPE * x; }

// ---------------- column stats (mean/var prep) over [nrows,128] ----------------
__global__ __launch_bounds__(256) void col_stats_kernel(const float* __restrict__ X, int nrows,
                                                        float* __restrict__ sum, float* __restrict__ ssum) {
    int tid = threadIdx.x;
    int c = tid & 127, half = tid >> 7;
    int rows_per = (nrows + gridDim.x - 1) / gridDim.x;
    int r0 = blockIdx.x * rows_per;
    int r1 = r0 + rows_per; if (r1 > nrows) r1 = nrows;
    float s = 0.f, ss = 0.f;
    for (int r = r0 + half; r < r1; r += 2) {
        float v = X[(size_t)r * 128 + c];
        s += v; ss += v * v;
    }
    __shared__ float sm1[256], sm2[256];
    sm1[tid] = s; sm2[tid] = ss;
    __syncthreads();
    if (tid < 128) {
        s = sm1[tid] + sm1[tid + 128];
        ss = sm2[tid] + sm2[tid + 128];
        atomicAdd(&sum[c], s);
        atomicAdd(&ssum[c], ss);
    }
}

// ---------------- BN fold: Wp[k][j] = a_k*W[k][j], hbias[j] = sum_k b_k*W[k][j] ----------------
__global__ __launch_bounds__(128) void bn_prep_kernel(const float* __restrict__ sum, const float* __restrict__ ssum,
                                                      const float* __restrict__ gamma, const float* __restrict__ beta,
                                                      const float* __restrict__ W, int J, float inv_n,
                                                      float* __restrict__ Wp, float* __restrict__ hb) {
    int k = threadIdx.x; // 128
    float mean = sum[k] * inv_n;
    float var = ssum[k] * inv_n - mean * mean;
    float a = gamma[k] * rsqrtf(var + 1e-5f);
    float b = beta[k] - mean * a;
    for (int j = 0; j < J; j++) Wp[k * J + j] = a * W[k * J + j];
    __shared__ float bs[128];
    bs[k] = b;
    __syncthreads();
    if (k < J) {
        float acc = 0.f;
        for (int kk = 0; kk < 128; kk++) acc += bs[kk] * W[kk * J + k];
        hb[k] = acc;
    }
}

// ---------------- GEMM1: H[N,128] = X[N,128] @ Wp[128,128] + hbias ----------------
__global__ __launch_bounds__(256) void gemm1_kernel(const float* __restrict__ X, const float* __restrict__ Wp,
                                                    const float* __restrict__ hbias, float* __restrict__ H, int nrows) {
    __shared__ float xs[64][36];    // 64 rows x 32 k-chunk, pad to 36
    __shared__ float wsm[32][128];  // k-chunk x 128 cols
    int tid = threadIdx.x;
    int ty = tid >> 4, tx = tid & 15;
    int r0 = blockIdx.x * 64;
    float acc[4][8];
#pragma unroll
    for (int i = 0; i < 4; i++)
#pragma unroll
        for (int j = 0; j < 8; j++) acc[i][j] = 0.f;

    for (int kb = 0; kb < 128; kb += 32) {
        // load x tile: 64x32 floats = 512 float4
        for (int u = tid; u < 512; u += 256) {
            int row = u >> 3, c4 = u & 7;
            float4 v = make_float4(0.f, 0.f, 0.f, 0.f);
            int gr = r0 + row;
            if (gr < nrows) v = *(const float4*)&X[(size_t)gr * 128 + kb + c4 * 4];
            *(float4*)&xs[row][c4 * 4] = v;
        }
        // load W tile: 32x128 = 1024 float4
        for (int u = tid; u < 1024; u += 256) {
            int kk = u >> 5, c4 = u & 31;
            *(float4*)&wsm[kk][c4 * 4] = *(const float4*)&Wp[(size_t)(kb + kk) * 128 + c4 * 4];
        }
        __syncthreads();
#pragma unroll
        for (int k = 0; k < 32; k++) {
            float xv[4];
#pragma unroll
            for (int i = 0; i < 4; i++) xv[i] = xs[ty * 4 + i][k];
            float4 wa = *(float4*)&wsm[k][tx * 8];
            float4 wb = *(float4*)&wsm[k][tx * 8 + 4];
            float wv[8] = {wa.x, wa.y, wa.z, wa.w, wb.x, wb.y, wb.z, wb.w};
#pragma unroll
            for (int i = 0; i < 4; i++)
#pragma unroll
                for (int j = 0; j < 8; j++) acc[i][j] += xv[i] * wv[j];
        }
        __syncthreads();
    }
    float4 hb0 = *(const float4*)&hbias[tx * 8];
    float4 hb1 = *(const float4*)&hbias[tx * 8 + 4];
#pragma unroll
    for (int i = 0; i < 4; i++) {
        int gr = r0 + ty * 4 + i;
        if (gr < nrows) {
            float4 o0 = make_float4(acc[i][0] + hb0.x, acc[i][1] + hb0.y, acc[i][2] + hb0.z, acc[i][3] + hb0.w);
            float4 o1 = make_float4(acc[i][4] + hb1.x, acc[i][5] + hb1.y, acc[i][6] + hb1.z, acc[i][7] + hb1.w);
            *(float4*)&H[(size_t)gr * 128 + tx * 8] = o0;
            *(float4*)&H[(size_t)gr * 128 + tx * 8 + 4] = o1;
        }
    }
}

// ---------------- node attention coefficients layer 1: as[n,h], ad[n,h] ----------------
__global__ __launch_bounds__(256) void node_attn1_kernel(const float* __restrict__ H, const float* __restrict__ att_s,
                                                         const float* __restrict__ att_d, float* __restrict__ as_o,
                                                         float* __restrict__ ad_o, int nn) {
    __shared__ float ssm[128], dsm[128];
    int tid = threadIdx.x;
    if (tid < 128) { ssm[tid] = att_s[tid]; dsm[tid] = att_d[tid]; }
    __syncthreads();
    int id = blockIdx.x * 256 + tid;
    if (id >= nn * 4) return;
    int n = id >> 2, h = id & 3;
    const float* hp = &H[(size_t)n * 128 + h * 32];
    const float* sp = &ssm[h * 32];
    const float* dp = &dsm[h * 32];
    float s = 0.f, d = 0.f;
#pragma unroll
    for (int k = 0; k < 32; k += 4) {
        float4 v = *(const float4*)&hp[k];
        s += v.x * sp[k] + v.y * sp[k + 1] + v.z * sp[k + 2] + v.w * sp[k + 3];
        d += v.x * dp[k] + v.y * dp[k + 1] + v.z * dp[k + 2] + v.w * dp[k + 3];
    }
    as_o[id] = s;
    ad_o[id] = d;
}

// ---------------- CSR build ----------------
__global__ __launch_bounds__(256) void deg_hist_kernel(const int* __restrict__ dst, int* __restrict__ deg, int ne) {
    int e = blockIdx.x * 256 + threadIdx.x;
    if (e < ne) atomicAdd(&deg[dst[e]], 1);
}

__global__ __launch_bounds__(1024) void scan_kernel(const int* __restrict__ deg, int n, int* __restrict__ rowptr,
                                                    int* __restrict__ cursor) {
    const int T = 1024;
    int tid = threadIdx.x;
    int chunk = (n + T - 1) / T;
    int s0 = tid * chunk;
    int s1 = s0 + chunk; if (s1 > n) s1 = n;
    int sum = 0;
    for (int i = s0; i < s1; i++) sum += deg[i];
    __shared__ int sm[T];
    sm[tid] = sum;
    __syncthreads();
    for (int off = 1; off < T; off <<= 1) {
        int t = (tid >= off) ? sm[tid - off] : 0;
        __syncthreads();
        sm[tid] += t;
        __syncthreads();
    }
    int run = sm[tid] - sum; // exclusive prefix
    for (int i = s0; i < s1; i++) {
        rowptr[i] = run;
        cursor[i] = run;
        run += deg[i];
    }
    if (tid == T - 1) rowptr[n] = sm[T - 1];
}

__global__ __launch_bounds__(256) void scatter_kernel(const int* __restrict__ src, const int* __restrict__ dst,
                                                      int* __restrict__ cursor, int* __restrict__ csr_src, int ne) {
    int e = blockIdx.x * 256 + threadIdx.x;
    if (e < ne) {
        int d = dst[e];
        int pos = atomicAdd(&cursor[d], 1);
        csr_src[pos] = src[e];
    }
}

// ---------------- GAT layer 1 aggregation: wave per node, 2 ch/lane, head=lane>>4 ----------------
__global__ __launch_bounds__(256) void gat1_agg_kernel(const float* __restrict__ H, const float* __restrict__ as1,
                                                       const float* __restrict__ ad1, const int* __restrict__ rowptr,
                                                       const int* __restrict__ csr_src, const float* __restrict__ bias1,
                                                       float* __restrict__ out) {
    int n = blockIdx.x * 4 + (threadIdx.x >> 6);
    int lane = threadIdx.x & 63;
    int h = lane >> 4;       // head for this lane's channels
    int c = lane * 2;        // channels c, c+1
    int start = rowptr[n], end = rowptr[n + 1];
    float adh = ad1[n * 4 + h];
    float ash_self = as1[n * 4 + h];
    float m = lrelu(ash_self + adh);
    // pass 1: per-head max over all incoming edges (16-lane group covers all edges)
    for (int i = start + (lane & 15); i < end; i += 16) {
        int s = csr_src[i];
        m = fmaxf(m, lrelu(as1[s * 4 + h] + adh));
    }
    m = fmaxf(m, __shfl_xor(m, 1));
    m = fmaxf(m, __shfl_xor(m, 2));
    m = fmaxf(m, __shfl_xor(m, 4));
    m = fmaxf(m, __shfl_xor(m, 8));
    // pass 2: weighted accumulate (self edge first)
    float den, a0, a1;
    {
        float p = expf(lrelu(ash_self + adh) - m);
        den = p;
        float2 hv = *(const float2*)&H[(size_t)n * 128 + c];
        a0 = p * hv.x;
        a1 = p * hv.y;
    }
    for (int i = start; i < end; i++) {
        int s = __builtin_amdgcn_readfirstlane(csr_src[i]);
        float p = expf(lrelu(as1[s * 4 + h] + adh) - m);
        den += p;
        float2 hv = *(const float2*)&H[(size_t)s * 128 + c];
        a0 += p * hv.x;
        a1 += p * hv.y;
    }
    float2 bv = *(const float2*)&bias1[c];
    float o0 = fmaxf(a0 / den + bv.x, 0.f);  // + bias1, ReLU fused
    float o1 = fmaxf(a1 / den + bv.y, 0.f);
    *(float2*)&out[(size_t)n * 128 + c] = make_float2(o0, o1);
}

// ---------------- GEMM2 (N,128)@(128,16) + fused as2/ad2 epilogue ----------------
__global__ __launch_bounds__(256) void gemm2_kernel(const float* __restrict__ X, const float* __restrict__ Wp,
                                                    const float* __restrict__ hb, const float* __restrict__ atts,
                                                    const float* __restrict__ attd, float* __restrict__ H2,
                                                    float* __restrict__ as_o, float* __restrict__ ad_o) {
    __shared__ float xs[16][129];
    __shared__ float wsm[128][16];
    __shared__ float hbs[16], ats[16], atd[16];
    int tid = threadIdx.x;
    if (tid < 16) { hbs[tid] = hb[tid]; ats[tid] = atts[tid]; atd[tid] = attd[tid]; }
    for (int u = tid; u < 2048; u += 256) wsm[u >> 4][u & 15] = Wp[u];
    int r0 = blockIdx.x * 16;
    for (int u = tid; u < 2048; u += 256) {
        int row = u >> 7, cc = u & 127;
        xs[row][cc] = X[(size_t)(r0 + row) * 128 + cc];
    }
    __syncthreads();
    int r = tid >> 4, c = tid & 15;
    float acc = 0.f;
#pragma unroll 8
    for (int k = 0; k < 128; k++) acc += xs[r][k] * wsm[k][c];
    acc += hbs[c];
    H2[(size_t)(r0 + r) * 16 + c] = acc;
    float s = acc * ats[c], d = acc * atd[c];
#pragma unroll
    for (int off = 1; off < 16; off <<= 1) {
        s += __shfl_xor(s, off);
        d += __shfl_xor(d, off);
    }
    if (c == 0) { as_o[r0 + r] = s; ad_o[r0 + r] = d; }
}

// ---------------- GAT layer 2 aggregation + bias + GELU ----------------
__global__ __launch_bounds__(256) void gat2_agg_kernel(const float* __restrict__ H2, const float* __restrict__ as2,
                                                       const float* __restrict__ ad2, const int* __restrict__ rowptr,
                                                       const int* __restrict__ csr_src, const float* __restrict__ bias2,
                                                       float* __restrict__ out) {
    int n = blockIdx.x * 4 + (threadIdx.x >> 6);
    int lane = threadIdx.x & 63;
    int sub = lane >> 4;  // edge subgroup 0..3
    int c = lane & 15;    // channel
    int start = rowptr[n], end = rowptr[n + 1];
    float adn = ad2[n], asn = as2[n];
    float m = lrelu(asn + adn);
    for (int i = start + lane; i < end; i += 64) {
        m = fmaxf(m, lrelu(as2[csr_src[i]] + adn));
    }
    m = fmaxf(m, __shfl_xor(m, 1));
    m = fmaxf(m, __shfl_xor(m, 2));
    m = fmaxf(m, __shfl_xor(m, 4));
    m = fmaxf(m, __shfl_xor(m, 8));
    m = fmaxf(m, __shfl_xor(m, 16));
    m = fmaxf(m, __shfl_xor(m, 32));
    float den = 0.f, acc = 0.f;
    if (sub == 0) {
        float p = expf(lrelu(asn + adn) - m);
        den = p;
        acc = p * H2[(size_t)n * 16 + c];
    }
    for (int i = start + sub; i < end; i += 4) {
        int s = csr_src[i];
        float p = expf(lrelu(as2[s] + adn) - m);
        den += p;
        acc += p * H2[(size_t)s * 16 + c];
    }
    acc += __shfl_xor(acc, 16);
    acc += __shfl_xor(acc, 32);
    den += __shfl_xor(den, 16);
    den += __shfl_xor(den, 32);
    float xo = acc / den + bias2[c];
    float t = tanhf(0.7978845608028654f * (xo + 0.044715f * xo * xo * xo));
    float g = 0.5f * xo * (1.f + t);
    if (sub == 0) out[(size_t)n * 16 + c] = g;
}

// ---------------- mean pool per graph + log_softmax ----------------
__global__ __launch_bounds__(256) void pool_lsm_kernel(const float* __restrict__ X, const int* __restrict__ batch,
                                                       int nn, float* __restrict__ out) {
    int g = blockIdx.x;
    int tid = threadIdx.x;
    int lo = 0, hi = nn;
    while (lo < hi) { int mid = (lo + hi) >> 1; if (batch[mid] < g) lo = mid + 1; else hi = mid; }
    int s = lo;
    lo = s; hi = nn;
    while (lo < hi) { int mid = (lo + hi) >> 1; if (batch[mid] < g + 1) lo = mid + 1; else hi = mid; }
    int e2 = lo;
    int c = tid & 15, grp = tid >> 4;
    float acc = 0.f;
    for (int r = s + grp; r < e2; r += 16) acc += X[(size_t)r * 16 + c];
    __shared__ float sm[256];
    sm[tid] = acc;
    __syncthreads();
    for (int off = 8; off >= 1; off >>= 1) {
        if (grp < off) sm[tid] += sm[tid + off * 16];
        __syncthreads();
    }
    if (tid < 16) {
        float cnt = (float)(e2 - s);
        float v = sm[tid] / fmaxf(cnt, 1.f);
        float mx = v;
        mx = fmaxf(mx, __shfl_xor(mx, 1));
        mx = fmaxf(mx, __shfl_xor(mx, 2));
        mx = fmaxf(mx, __shfl_xor(mx, 4));
        mx = fmaxf(mx, __shfl_xor(mx, 8));
        float ex = expf(v - mx);
        float ssum = ex;
        ssum += __shfl_xor(ssum, 1);
        ssum += __shfl_xor(ssum, 2);
        ssum += __shfl_xor(ssum, 4);
        ssum += __shfl_xor(ssum, 8);
        out[g * 16 + tid] = v - mx - logf(ssum);
    }
}

extern "C" void kernel_launch(void* const* d_in, const int* in_sizes, int n_in,
                              void* d_out, int out_size, void* d_ws, size_t ws_size,
                              hipStream_t stream) {
    const float* x        = (const float*)d_in[0];
    const float* W1       = (const float*)d_in[1];
    const float* att_src1 = (const float*)d_in[2];
    const float* att_dst1 = (const float*)d_in[3];
    const float* bias1    = (const float*)d_in[4];
    const float* W2       = (const float*)d_in[5];
    const float* att_src2 = (const float*)d_in[6];
    const float* att_dst2 = (const float*)d_in[7];
    const float* bias2    = (const float*)d_in[8];
    const float* bn1g     = (const float*)d_in[9];
    const float* bn1b     = (const float*)d_in[10];
    const float* bn2g     = (const float*)d_in[11];
    const float* bn2b     = (const float*)d_in[12];
    const int*   ei       = (const int*)d_in[13];
    const int*   batch    = (const int*)d_in[14];
    float* out = (float*)d_out;

    char* p = (char*)d_ws;
    auto alloc = [&](size_t bytes) -> char* {
        char* r = p;
        p += (bytes + 255) & ~(size_t)255;
        return r;
    };
    float* bnbuf   = (float*)alloc(512 * sizeof(float));       // bn1sum|bn1ss|bn2sum|bn2ss
    int*   deg     = (int*)alloc(NN * sizeof(int));             // contiguous with bnbuf (zero region)
    int*   rowptr  = (int*)alloc((NN + 1) * sizeof(int));
    int*   cursor  = (int*)alloc(NN * sizeof(int));
    int*   csr_src = (int*)alloc(NE * sizeof(int));
    float* W1p     = (float*)alloc(128 * 128 * sizeof(float));
    float* h1bias  = (float*)alloc(128 * sizeof(float));
    float* h1      = (float*)alloc((size_t)NN * 128 * sizeof(float));
    float* as1     = (float*)alloc((size_t)NN * 4 * sizeof(float));
    float* ad1     = (float*)alloc((size_t)NN * 4 * sizeof(float));
    float* out1    = (float*)alloc((size_t)NN * 128 * sizeof(float));
    float* W2p     = (float*)alloc(128 * 16 * sizeof(float));
    float* h2bias  = (float*)alloc(16 * sizeof(float));
    float* h2      = (float*)alloc((size_t)NN * 16 * sizeof(float));
    float* as2     = (float*)alloc(NN * sizeof(float));
    float* ad2     = (float*)alloc(NN * sizeof(float));
    float* out2g   = (float*)alloc((size_t)NN * 16 * sizeof(float));

    float* bn1sum = bnbuf;
    float* bn1ss  = bnbuf + 128;
    float* bn2sum = bnbuf + 256;
    float* bn2ss  = bnbuf + 384;
    const int* esrc = ei;
    const int* edst = ei + NE;

    // zero: bn stats (2048B) + deg (200000B) are contiguous
    hipMemsetAsync(bnbuf, 0, 512 * sizeof(float) + NN * sizeof(int), stream);

    const float inv_n = 1.f / (float)NN;

    col_stats_kernel<<<256, 256, 0, stream>>>(x, NN, bn1sum, bn1ss);
    bn_prep_kernel<<<1, 128, 0, stream>>>(bn1sum, bn1ss, bn1g, bn1b, W1, 128, inv_n, W1p, h1bias);
    gemm1_kernel<<<(NN + 63) / 64, 256, 0, stream>>>(x, W1p, h1bias, h1, NN);
    node_attn1_kernel<<<(NN * 4 + 255) / 256, 256, 0, stream>>>(h1, att_src1, att_dst1, as1, ad1, NN);
    deg_hist_kernel<<<(NE + 255) / 256, 256, 0, stream>>>(edst, deg, NE);
    scan_kernel<<<1, 1024, 0, stream>>>(deg, NN, rowptr, cursor);
    scatter_kernel<<<(NE + 255) / 256, 256, 0, stream>>>(esrc, edst, cursor, csr_src, NE);
    gat1_agg_kernel<<<NN / 4, 256, 0, stream>>>(h1, as1, ad1, rowptr, csr_src, bias1, out1);
    col_stats_kernel<<<256, 256, 0, stream>>>(out1, NN, bn2sum, bn2ss);
    bn_prep_kernel<<<1, 128, 0, stream>>>(bn2sum, bn2ss, bn2g, bn2b, W2, 16, inv_n, W2p, h2bias);
    gemm2_kernel<<<NN / 16, 256, 0, stream>>>(out1, W2p, h2bias, att_src2, att_dst2, h2, as2, ad2);
    gat2_agg_kernel<<<NN / 4, 256, 0, stream>>>(h2, as2, ad2, rowptr, csr_src, bias2, out2g);
    pool_lsm_kernel<<<NG, 256, 0, stream>>>(out2g, batch, NN, out);
}

// Round 2
// 549.040 us; speedup vs baseline: 1.0697x; 1.0697x over previous
//
#include <hip/hip_runtime.h>
#include <math.h>
#include <stdint.h>

#define NN 50000
#define NE 800000
#define NG 64
#define NEG_SLOPE 0.2f

__device__ __forceinline__ float lrelu(float x) { return x > 0.f ? x : NEG_SLOPE * x; }

// ---------------- column stats (mean/var prep) over [nrows,128] ----------------
__global__ __launch_bounds__(256) void col_stats_kernel(const float* __restrict__ X, int nrows,
                                                        float* __restrict__ sum, float* __restrict__ ssum) {
    int tid = threadIdx.x;
    int c = tid & 127, half = tid >> 7;
    int rows_per = (nrows + gridDim.x - 1) / gridDim.x;
    int r0 = blockIdx.x * rows_per;
    int r1 = r0 + rows_per; if (r1 > nrows) r1 = nrows;
    float s = 0.f, ss = 0.f;
    for (int r = r0 + half; r < r1; r += 2) {
        float v = X[(size_t)r * 128 + c];
        s += v; ss += v * v;
    }
    __shared__ float sm1[256], sm2[256];
    sm1[tid] = s; sm2[tid] = ss;
    __syncthreads();
    if (tid < 128) {
        s = sm1[tid] + sm1[tid + 128];
        ss = sm2[tid] + sm2[tid + 128];
        atomicAdd(&sum[c], s);
        atomicAdd(&ssum[c], ss);
    }
}

// ---------------- BN fold: Wp[k][j] = a_k*W[k][j], hbias[j] = sum_k b_k*W[k][j] ----------------
__global__ __launch_bounds__(128) void bn_prep_kernel(const float* __restrict__ sum, const float* __restrict__ ssum,
                                                      const float* __restrict__ gamma, const float* __restrict__ beta,
                                                      const float* __restrict__ W, int J, float inv_n,
                                                      float* __restrict__ Wp, float* __restrict__ hb) {
    int k = threadIdx.x; // 128
    float mean = sum[k] * inv_n;
    float var = ssum[k] * inv_n - mean * mean;
    float a = gamma[k] * rsqrtf(var + 1e-5f);
    float b = beta[k] - mean * a;
    for (int j = 0; j < J; j++) Wp[k * J + j] = a * W[k * J + j];
    __shared__ float bs[128];
    bs[k] = b;
    __syncthreads();
    if (k < J) {
        float acc = 0.f;
        for (int kk = 0; kk < 128; kk++) acc += bs[kk] * W[kk * J + k];
        hb[k] = acc;
    }
}

// ---------------- GEMM1: H[N,128] = X[N,128] @ Wp[128,128] + hbias ----------------
__global__ __launch_bounds__(256) void gemm1_kernel(const float* __restrict__ X, const float* __restrict__ Wp,
                                                    const float* __restrict__ hbias, float* __restrict__ H, int nrows) {
    __shared__ float xs[64][36];    // 64 rows x 32 k-chunk, pad to 36
    __shared__ float wsm[32][128];  // k-chunk x 128 cols
    int tid = threadIdx.x;
    int ty = tid >> 4, tx = tid & 15;
    int r0 = blockIdx.x * 64;
    float acc[4][8];
#pragma unroll
    for (int i = 0; i < 4; i++)
#pragma unroll
        for (int j = 0; j < 8; j++) acc[i][j] = 0.f;

    for (int kb = 0; kb < 128; kb += 32) {
        for (int u = tid; u < 512; u += 256) {
            int row = u >> 3, c4 = u & 7;
            float4 v = make_float4(0.f, 0.f, 0.f, 0.f);
            int gr = r0 + row;
            if (gr < nrows) v = *(const float4*)&X[(size_t)gr * 128 + kb + c4 * 4];
            *(float4*)&xs[row][c4 * 4] = v;
        }
        for (int u = tid; u < 1024; u += 256) {
            int kk = u >> 5, c4 = u & 31;
            *(float4*)&wsm[kk][c4 * 4] = *(const float4*)&Wp[(size_t)(kb + kk) * 128 + c4 * 4];
        }
        __syncthreads();
#pragma unroll
        for (int k = 0; k < 32; k++) {
            float xv[4];
#pragma unroll
            for (int i = 0; i < 4; i++) xv[i] = xs[ty * 4 + i][k];
            float4 wa = *(float4*)&wsm[k][tx * 8];
            float4 wb = *(float4*)&wsm[k][tx * 8 + 4];
            float wv[8] = {wa.x, wa.y, wa.z, wa.w, wb.x, wb.y, wb.z, wb.w};
#pragma unroll
            for (int i = 0; i < 4; i++)
#pragma unroll
                for (int j = 0; j < 8; j++) acc[i][j] += xv[i] * wv[j];
        }
        __syncthreads();
    }
    float4 hb0 = *(const float4*)&hbias[tx * 8];
    float4 hb1 = *(const float4*)&hbias[tx * 8 + 4];
#pragma unroll
    for (int i = 0; i < 4; i++) {
        int gr = r0 + ty * 4 + i;
        if (gr < nrows) {
            float4 o0 = make_float4(acc[i][0] + hb0.x, acc[i][1] + hb0.y, acc[i][2] + hb0.z, acc[i][3] + hb0.w);
            float4 o1 = make_float4(acc[i][4] + hb1.x, acc[i][5] + hb1.y, acc[i][6] + hb1.z, acc[i][7] + hb1.w);
            *(float4*)&H[(size_t)gr * 128 + tx * 8] = o0;
            *(float4*)&H[(size_t)gr * 128 + tx * 8 + 4] = o1;
        }
    }
}

// ---------------- node attention coefficients layer 1: as[n,h], ad[n,h] ----------------
__global__ __launch_bounds__(256) void node_attn1_kernel(const float* __restrict__ H, const float* __restrict__ att_s,
                                                         const float* __restrict__ att_d, float* __restrict__ as_o,
                                                         float* __restrict__ ad_o, int nn) {
    __shared__ float ssm[128], dsm[128];
    int tid = threadIdx.x;
    if (tid < 128) { ssm[tid] = att_s[tid]; dsm[tid] = att_d[tid]; }
    __syncthreads();
    int id = blockIdx.x * 256 + tid;
    if (id >= nn * 4) return;
    int n = id >> 2, h = id & 3;
    const float* hp = &H[(size_t)n * 128 + h * 32];
    const float* sp = &ssm[h * 32];
    const float* dp = &dsm[h * 32];
    float s = 0.f, d = 0.f;
#pragma unroll
    for (int k = 0; k < 32; k += 4) {
        float4 v = *(const float4*)&hp[k];
        s += v.x * sp[k] + v.y * sp[k + 1] + v.z * sp[k + 2] + v.w * sp[k + 3];
        d += v.x * dp[k] + v.y * dp[k + 1] + v.z * dp[k + 2] + v.w * dp[k + 3];
    }
    as_o[id] = s;
    ad_o[id] = d;
}

// ---------------- CSR build ----------------
__global__ __launch_bounds__(256) void deg_hist_kernel(const int* __restrict__ dst, int* __restrict__ deg, int ne) {
    int e = blockIdx.x * 256 + threadIdx.x;
    if (e < ne) atomicAdd(&deg[dst[e]], 1);
}

__global__ __launch_bounds__(1024) void scan_kernel(const int* __restrict__ deg, int n, int* __restrict__ rowptr,
                                                    int* __restrict__ cursor) {
    const int T = 1024;
    int tid = threadIdx.x;
    int chunk = (n + T - 1) / T;
    int s0 = tid * chunk;
    int s1 = s0 + chunk; if (s1 > n) s1 = n;
    int sum = 0;
    for (int i = s0; i < s1; i++) sum += deg[i];
    __shared__ int sm[T];
    sm[tid] = sum;
    __syncthreads();
    for (int off = 1; off < T; off <<= 1) {
        int t = (tid >= off) ? sm[tid - off] : 0;
        __syncthreads();
        sm[tid] += t;
        __syncthreads();
    }
    int run = sm[tid] - sum; // exclusive prefix
    for (int i = s0; i < s1; i++) {
        rowptr[i] = run;
        cursor[i] = run;
        run += deg[i];
    }
    if (tid == T - 1) rowptr[n] = sm[T - 1];
}

__global__ __launch_bounds__(256) void scatter_kernel(const int* __restrict__ src, const int* __restrict__ dst,
                                                      int* __restrict__ cursor, int* __restrict__ csr_src, int ne) {
    int e = blockIdx.x * 256 + threadIdx.x;
    if (e < ne) {
        int d = dst[e];
        int pos = atomicAdd(&cursor[d], 1);
        csr_src[pos] = src[e];
    }
}

// ---------------- GAT layer 1 aggregation ----------------
// Wave per node. Lane-parallel edge phase (idx + all-4-head exp), then pairwise
// aggregation: half-wave (32 lanes x float4) per edge, 2 edges in flight.
__global__ __launch_bounds__(256) void gat1_agg_kernel(const float* __restrict__ H, const float* __restrict__ as1,
                                                       const float* __restrict__ ad1, const int* __restrict__ rowptr,
                                                       const int* __restrict__ csr_src, const float* __restrict__ bias1,
                                                       float* __restrict__ out) {
    int n = blockIdx.x * 4 + (threadIdx.x >> 6);
    int lane = threadIdx.x & 63;
    int half = lane >> 5;     // which edge of the in-flight pair
    int within = lane & 31;
    int c4 = within * 4;      // channels [c4..c4+3]
    int headc = within >> 3;  // head of this channel group
    int start = rowptr[n], end = rowptr[n + 1];

    float4 ad4 = *(const float4*)&ad1[n * 4];
    float4 as4s = *(const float4*)&as1[n * 4];
    float es0 = lrelu(as4s.x + ad4.x);
    float es1 = lrelu(as4s.y + ad4.y);
    float es2 = lrelu(as4s.z + ad4.z);
    float es3 = lrelu(as4s.w + ad4.w);

    // pass A: per-head max (self included), lane-parallel over edges
    float m0 = es0, m1 = es1, m2 = es2, m3 = es3;
    for (int base = start; base < end; base += 64) {
        int i = base + lane;
        if (i < end) {
            int s = csr_src[i];
            float4 a = *(const float4*)&as1[(size_t)s * 4];
            m0 = fmaxf(m0, lrelu(a.x + ad4.x));
            m1 = fmaxf(m1, lrelu(a.y + ad4.y));
            m2 = fmaxf(m2, lrelu(a.z + ad4.z));
            m3 = fmaxf(m3, lrelu(a.w + ad4.w));
        }
    }
#pragma unroll
    for (int off = 1; off < 64; off <<= 1) {
        m0 = fmaxf(m0, __shfl_xor(m0, off));
        m1 = fmaxf(m1, __shfl_xor(m1, off));
        m2 = fmaxf(m2, __shfl_xor(m2, off));
        m3 = fmaxf(m3, __shfl_xor(m3, off));
    }

    // self contribution: den on lane 0 only; acc on half 0 only
    float d0 = 0.f, d1 = 0.f, d2 = 0.f, d3 = 0.f;
    if (lane == 0) {
        d0 = __expf(es0 - m0); d1 = __expf(es1 - m1);
        d2 = __expf(es2 - m2); d3 = __expf(es3 - m3);
    }
    float acc0 = 0.f, acc1 = 0.f, acc2 = 0.f, acc3 = 0.f;
    {
        float msel = (headc == 0) ? m0 : (headc == 1) ? m1 : (headc == 2) ? m2 : m3;
        float esel = (headc == 0) ? es0 : (headc == 1) ? es1 : (headc == 2) ? es2 : es3;
        float pself = __expf(esel - msel);
        if (half == 0) {
            float4 hv = *(const float4*)&H[(size_t)n * 128 + c4];
            acc0 = pself * hv.x; acc1 = pself * hv.y;
            acc2 = pself * hv.z; acc3 = pself * hv.w;
        }
    }

    // pass B: lane-parallel weights, pairwise aggregation
    for (int base = start; base < end; base += 64) {
        int i = base + lane;
        int s = 0;
        float p0 = 0.f, p1 = 0.f, p2 = 0.f, p3 = 0.f;
        if (i < end) {
            s = csr_src[i];
            float4 a = *(const float4*)&as1[(size_t)s * 4];
            p0 = __expf(lrelu(a.x + ad4.x) - m0);
            p1 = __expf(lrelu(a.y + ad4.y) - m1);
            p2 = __expf(lrelu(a.z + ad4.z) - m2);
            p3 = __expf(lrelu(a.w + ad4.w) - m3);
            d0 += p0; d1 += p1; d2 += p2; d3 += p3;
        }
        int cnt = min(64, end - base);
#pragma unroll 2
        for (int j = 0; j < cnt; j += 2) {
            int jj = j + half;
            int s0 = __shfl(s, jj);
            float q0 = __shfl(p0, jj);
            float q1 = __shfl(p1, jj);
            float q2 = __shfl(p2, jj);
            float q3 = __shfl(p3, jj);
            float p = (headc == 0) ? q0 : (headc == 1) ? q1 : (headc == 2) ? q2 : q3;
            if (jj < cnt) {
                float4 hv = *(const float4*)&H[(size_t)s0 * 128 + c4];
                acc0 += p * hv.x; acc1 += p * hv.y;
                acc2 += p * hv.z; acc3 += p * hv.w;
            }
        }
    }

    // reduce den over lanes; fold edge halves of acc
#pragma unroll
    for (int off = 1; off < 64; off <<= 1) {
        d0 += __shfl_xor(d0, off);
        d1 += __shfl_xor(d1, off);
        d2 += __shfl_xor(d2, off);
        d3 += __shfl_xor(d3, off);
    }
    acc0 += __shfl_xor(acc0, 32);
    acc1 += __shfl_xor(acc1, 32);
    acc2 += __shfl_xor(acc2, 32);
    acc3 += __shfl_xor(acc3, 32);

    if (half == 0) {
        float den = (headc == 0) ? d0 : (headc == 1) ? d1 : (headc == 2) ? d2 : d3;
        float inv = 1.f / den;
        float4 bv = *(const float4*)&bias1[c4];
        float4 o;
        o.x = fmaxf(acc0 * inv + bv.x, 0.f);
        o.y = fmaxf(acc1 * inv + bv.y, 0.f);
        o.z = fmaxf(acc2 * inv + bv.z, 0.f);
        o.w = fmaxf(acc3 * inv + bv.w, 0.f);
        *(float4*)&out[(size_t)n * 128 + c4] = o;
    }
}

// ---------------- GEMM2 (N,128)@(128,16) + fused as2/ad2 epilogue ----------------
__global__ __launch_bounds__(256) void gemm2_kernel(const float* __restrict__ X, const float* __restrict__ Wp,
                                                    const float* __restrict__ hb, const float* __restrict__ atts,
                                                    const float* __restrict__ attd, float* __restrict__ H2,
                                                    float* __restrict__ as_o, float* __restrict__ ad_o) {
    __shared__ float xs[16][129];
    __shared__ float wsm[128][16];
    __shared__ float hbs[16], ats[16], atd[16];
    int tid = threadIdx.x;
    if (tid < 16) { hbs[tid] = hb[tid]; ats[tid] = atts[tid]; atd[tid] = attd[tid]; }
    for (int u = tid; u < 2048; u += 256) wsm[u >> 4][u & 15] = Wp[u];
    int r0 = blockIdx.x * 16;
    for (int u = tid; u < 2048; u += 256) {
        int row = u >> 7, cc = u & 127;
        xs[row][cc] = X[(size_t)(r0 + row) * 128 + cc];
    }
    __syncthreads();
    int r = tid >> 4, c = tid & 15;
    float acc = 0.f;
#pragma unroll 8
    for (int k = 0; k < 128; k++) acc += xs[r][k] * wsm[k][c];
    acc += hbs[c];
    H2[(size_t)(r0 + r) * 16 + c] = acc;
    float s = acc * ats[c], d = acc * atd[c];
#pragma unroll
    for (int off = 1; off < 16; off <<= 1) {
        s += __shfl_xor(s, off);
        d += __shfl_xor(d, off);
    }
    if (c == 0) { as_o[r0 + r] = s; ad_o[r0 + r] = d; }
}

// ---------------- GAT layer 2 aggregation + bias + GELU ----------------
// Wave per node; 4 edges in flight (16 lanes x 4B per edge).
__global__ __launch_bounds__(256) void gat2_agg_kernel(const float* __restrict__ H2, const float* __restrict__ as2,
                                                       const float* __restrict__ ad2, const int* __restrict__ rowptr,
                                                       const int* __restrict__ csr_src, const float* __restrict__ bias2,
                                                       float* __restrict__ out) {
    int n = blockIdx.x * 4 + (threadIdx.x >> 6);
    int lane = threadIdx.x & 63;
    int quarter = lane >> 4;
    int c = lane & 15;
    int start = rowptr[n], end = rowptr[n + 1];
    float adn = ad2[n], asn = as2[n];
    float eself = lrelu(asn + adn);

    float m = eself;
    for (int base = start; base < end; base += 64) {
        int i = base + lane;
        if (i < end) m = fmaxf(m, lrelu(as2[csr_src[i]] + adn));
    }
#pragma unroll
    for (int off = 1; off < 64; off <<= 1) m = fmaxf(m, __shfl_xor(m, off));

    float den = (lane == 0) ? __expf(eself - m) : 0.f;
    float acc = 0.f;
    if (quarter == 0) acc = __expf(eself - m) * H2[(size_t)n * 16 + c];

    for (int base = start; base < end; base += 64) {
        int i = base + lane;
        int s = 0;
        float p = 0.f;
        if (i < end) {
            s = csr_src[i];
            p = __expf(lrelu(as2[s] + adn) - m);
            den += p;
        }
        int cnt = min(64, end - base);
#pragma unroll 2
        for (int j = 0; j < cnt; j += 4) {
            int jj = j + quarter;
            int s0 = __shfl(s, jj);
            float p0 = __shfl(p, jj);
            if (jj < cnt) acc += p0 * H2[(size_t)s0 * 16 + c];
        }
    }
#pragma unroll
    for (int off = 1; off < 64; off <<= 1) den += __shfl_xor(den, off);
    acc += __shfl_xor(acc, 16);
    acc += __shfl_xor(acc, 32);

    if (quarter == 0) {
        float xo = acc / den + bias2[c];
        float t = tanhf(0.7978845608028654f * (xo + 0.044715f * xo * xo * xo));
        out[(size_t)n * 16 + c] = 0.5f * xo * (1.f + t);
    }
}

// ---------------- mean pool per graph + log_softmax ----------------
__global__ __launch_bounds__(256) void pool_lsm_kernel(const float* __restrict__ X, const int* __restrict__ batch,
                                                       int nn, float* __restrict__ out) {
    int g = blockIdx.x;
    int tid = threadIdx.x;
    int lo = 0, hi = nn;
    while (lo < hi) { int mid = (lo + hi) >> 1; if (batch[mid] < g) lo = mid + 1; else hi = mid; }
    int s = lo;
    lo = s; hi = nn;
    while (lo < hi) { int mid = (lo + hi) >> 1; if (batch[mid] < g + 1) lo = mid + 1; else hi = mid; }
    int e2 = lo;
    int c = tid & 15, grp = tid >> 4;
    float acc = 0.f;
    for (int r = s + grp; r < e2; r += 16) acc += X[(size_t)r * 16 + c];
    __shared__ float sm[256];
    sm[tid] = acc;
    __syncthreads();
    for (int off = 8; off >= 1; off >>= 1) {
        if (grp < off) sm[tid] += sm[tid + off * 16];
        __syncthreads();
    }
    if (tid < 16) {
        float cnt = (float)(e2 - s);
        float v = sm[tid] / fmaxf(cnt, 1.f);
        float mx = v;
        mx = fmaxf(mx, __shfl_xor(mx, 1));
        mx = fmaxf(mx, __shfl_xor(mx, 2));
        mx = fmaxf(mx, __shfl_xor(mx, 4));
        mx = fmaxf(mx, __shfl_xor(mx, 8));
        float ex = __expf(v - mx);
        float ssum = ex;
        ssum += __shfl_xor(ssum, 1);
        ssum += __shfl_xor(ssum, 2);
        ssum += __shfl_xor(ssum, 4);
        ssum += __shfl_xor(ssum, 8);
        out[g * 16 + tid] = v - mx - __logf(ssum);
    }
}

extern "C" void kernel_launch(void* const* d_in, const int* in_sizes, int n_in,
                              void* d_out, int out_size, void* d_ws, size_t ws_size,
                              hipStream_t stream) {
    const float* x        = (const float*)d_in[0];
    const float* W1       = (const float*)d_in[1];
    const float* att_src1 = (const float*)d_in[2];
    const float* att_dst1 = (const float*)d_in[3];
    const float* bias1    = (const float*)d_in[4];
    const float* W2       = (const float*)d_in[5];
    const float* att_src2 = (const float*)d_in[6];
    const float* att_dst2 = (const float*)d_in[7];
    const float* bias2    = (const float*)d_in[8];
    const float* bn1g     = (const float*)d_in[9];
    const float* bn1b     = (const float*)d_in[10];
    const float* bn2g     = (const float*)d_in[11];
    const float* bn2b     = (const float*)d_in[12];
    const int*   ei       = (const int*)d_in[13];
    const int*   batch    = (const int*)d_in[14];
    float* out = (float*)d_out;

    char* p = (char*)d_ws;
    auto alloc = [&](size_t bytes) -> char* {
        char* r = p;
        p += (bytes + 255) & ~(size_t)255;
        return r;
    };
    float* bnbuf   = (float*)alloc(512 * sizeof(float));
    int*   deg     = (int*)alloc(NN * sizeof(int));  // contiguous with bnbuf (zero region)
    int*   rowptr  = (int*)alloc((NN + 1) * sizeof(int));
    int*   cursor  = (int*)alloc(NN * sizeof(int));
    int*   csr_src = (int*)alloc(NE * sizeof(int));
    float* W1p     = (float*)alloc(128 * 128 * sizeof(float));
    float* h1bias  = (float*)alloc(128 * sizeof(float));
    float* h1      = (float*)alloc((size_t)NN * 128 * sizeof(float));
    float* as1     = (float*)alloc((size_t)NN * 4 * sizeof(float));
    float* ad1     = (float*)alloc((size_t)NN * 4 * sizeof(float));
    float* out1    = (float*)alloc((size_t)NN * 128 * sizeof(float));
    float* W2p     = (float*)alloc(128 * 16 * sizeof(float));
    float* h2bias  = (float*)alloc(16 * sizeof(float));
    float* h2      = (float*)alloc((size_t)NN * 16 * sizeof(float));
    float* as2     = (float*)alloc(NN * sizeof(float));
    float* ad2     = (float*)alloc(NN * sizeof(float));
    float* out2g   = (float*)alloc((size_t)NN * 16 * sizeof(float));

    float* bn1sum = bnbuf;
    float* bn1ss  = bnbuf + 128;
    float* bn2sum = bnbuf + 256;
    float* bn2ss  = bnbuf + 384;
    const int* esrc = ei;
    const int* edst = ei + NE;

    hipMemsetAsync(bnbuf, 0, 512 * sizeof(float) + NN * sizeof(int), stream);

    const float inv_n = 1.f / (float)NN;

    col_stats_kernel<<<256, 256, 0, stream>>>(x, NN, bn1sum, bn1ss);
    bn_prep_kernel<<<1, 128, 0, stream>>>(bn1sum, bn1ss, bn1g, bn1b, W1, 128, inv_n, W1p, h1bias);
    gemm1_kernel<<<(NN + 63) / 64, 256, 0, stream>>>(x, W1p, h1bias, h1, NN);
    node_attn1_kernel<<<(NN * 4 + 255) / 256, 256, 0, stream>>>(h1, att_src1, att_dst1, as1, ad1, NN);
    deg_hist_kernel<<<(NE + 255) / 256, 256, 0, stream>>>(edst, deg, NE);
    scan_kernel<<<1, 1024, 0, stream>>>(deg, NN, rowptr, cursor);
    scatter_kernel<<<(NE + 255) / 256, 256, 0, stream>>>(esrc, edst, cursor, csr_src, NE);
    gat1_agg_kernel<<<NN / 4, 256, 0, stream>>>(h1, as1, ad1, rowptr, csr_src, bias1, out1);
    col_stats_kernel<<<256, 256, 0, stream>>>(out1, NN, bn2sum, bn2ss);
    bn_prep_kernel<<<1, 128, 0, stream>>>(bn2sum, bn2ss, bn2g, bn2b, W2, 16, inv_n, W2p, h2bias);
    gemm2_kernel<<<NN / 16, 256, 0, stream>>>(out1, W2p, h2bias, att_src2, att_dst2, h2, as2, ad2);
    gat2_agg_kernel<<<NN / 4, 256, 0, stream>>>(h2, as2, ad2, rowptr, csr_src, bias2, out2g);
    pool_lsm_kernel<<<NG, 256, 0, stream>>>(out2g, batch, NN, out);
}

// Round 4
// 462.605 us; speedup vs baseline: 1.2695x; 1.1868x over previous
//
#include <hip/hip_runtime.h>
#include <math.h>
#include <stdint.h>

#define NN 50000
#define NE 800000
#define NG 64
#define NEG_SLOPE 0.2f
#define NBLK ((NN + 255) / 256)   // 196 scan blocks

__device__ __forceinline__ float lrelu(float x) { return x > 0.f ? x : NEG_SLOPE * x; }

// ---------------- column stats (mean/var prep) over [nrows,128] ----------------
__global__ __launch_bounds__(256) void col_stats_kernel(const float* __restrict__ X, int nrows,
                                                        float* __restrict__ sum, float* __restrict__ ssum) {
    int tid = threadIdx.x;
    int c = tid & 127, half = tid >> 7;
    int rows_per = (nrows + gridDim.x - 1) / gridDim.x;
    int r0 = blockIdx.x * rows_per;
    int r1 = r0 + rows_per; if (r1 > nrows) r1 = nrows;
    float s = 0.f, ss = 0.f;
    for (int r = r0 + half; r < r1; r += 2) {
        float v = X[(size_t)r * 128 + c];
        s += v; ss += v * v;
    }
    __shared__ float sm1[256], sm2[256];
    sm1[tid] = s; sm2[tid] = ss;
    __syncthreads();
    if (tid < 128) {
        s = sm1[tid] + sm1[tid + 128];
        ss = sm2[tid] + sm2[tid + 128];
        atomicAdd(&sum[c], s);
        atomicAdd(&ssum[c], ss);
    }
}

// ---------------- BN fold: Wp[k][j] = a_k*W[k][j], hbias[j] = sum_k b_k*W[k][j] ----------------
__global__ __launch_bounds__(128) void bn_prep_kernel(const float* __restrict__ sum, const float* __restrict__ ssum,
                                                      const float* __restrict__ gamma, const float* __restrict__ beta,
                                                      const float* __restrict__ W, int J, float inv_n,
                                                      float* __restrict__ Wp, float* __restrict__ hb) {
    int k = threadIdx.x; // 128
    float mean = sum[k] * inv_n;
    float var = ssum[k] * inv_n - mean * mean;
    float a = gamma[k] * rsqrtf(var + 1e-5f);
    float b = beta[k] - mean * a;
    for (int j = 0; j < J; j++) Wp[k * J + j] = a * W[k * J + j];
    __shared__ float bs[128];
    bs[k] = b;
    __syncthreads();
    if (k < J) {
        float acc = 0.f;
        for (int kk = 0; kk < 128; kk++) acc += bs[kk] * W[kk * J + k];
        hb[k] = acc;
    }
}

// ---------------- GEMM1: H[N,128] = X[N,128] @ Wp[128,128] + hbias ----------------
__global__ __launch_bounds__(256) void gemm1_kernel(const float* __restrict__ X, const float* __restrict__ Wp,
                                                    const float* __restrict__ hbias, float* __restrict__ H, int nrows) {
    __shared__ float xs[64][36];    // 64 rows x 32 k-chunk, pad to 36
    __shared__ float wsm[32][128];  // k-chunk x 128 cols
    int tid = threadIdx.x;
    int ty = tid >> 4, tx = tid & 15;
    int r0 = blockIdx.x * 64;
    float acc[4][8];
#pragma unroll
    for (int i = 0; i < 4; i++)
#pragma unroll
        for (int j = 0; j < 8; j++) acc[i][j] = 0.f;

    for (int kb = 0; kb < 128; kb += 32) {
        for (int u = tid; u < 512; u += 256) {
            int row = u >> 3, c4 = u & 7;
            float4 v = make_float4(0.f, 0.f, 0.f, 0.f);
            int gr = r0 + row;
            if (gr < nrows) v = *(const float4*)&X[(size_t)gr * 128 + kb + c4 * 4];
            *(float4*)&xs[row][c4 * 4] = v;
        }
        for (int u = tid; u < 1024; u += 256) {
            int kk = u >> 5, c4 = u & 31;
            *(float4*)&wsm[kk][c4 * 4] = *(const float4*)&Wp[(size_t)(kb + kk) * 128 + c4 * 4];
        }
        __syncthreads();
#pragma unroll
        for (int k = 0; k < 32; k++) {
            float xv[4];
#pragma unroll
            for (int i = 0; i < 4; i++) xv[i] = xs[ty * 4 + i][k];
            float4 wa = *(float4*)&wsm[k][tx * 8];
            float4 wb = *(float4*)&wsm[k][tx * 8 + 4];
            float wv[8] = {wa.x, wa.y, wa.z, wa.w, wb.x, wb.y, wb.z, wb.w};
#pragma unroll
            for (int i = 0; i < 4; i++)
#pragma unroll
                for (int j = 0; j < 8; j++) acc[i][j] += xv[i] * wv[j];
        }
        __syncthreads();
    }
    float4 hb0 = *(const float4*)&hbias[tx * 8];
    float4 hb1 = *(const float4*)&hbias[tx * 8 + 4];
#pragma unroll
    for (int i = 0; i < 4; i++) {
        int gr = r0 + ty * 4 + i;
        if (gr < nrows) {
            float4 o0 = make_float4(acc[i][0] + hb0.x, acc[i][1] + hb0.y, acc[i][2] + hb0.z, acc[i][3] + hb0.w);
            float4 o1 = make_float4(acc[i][4] + hb1.x, acc[i][5] + hb1.y, acc[i][6] + hb1.z, acc[i][7] + hb1.w);
            *(float4*)&H[(size_t)gr * 128 + tx * 8] = o0;
            *(float4*)&H[(size_t)gr * 128 + tx * 8 + 4] = o1;
        }
    }
}

// ---------------- node attention coefficients layer 1: as[n,h], ad[n,h] ----------------
__global__ __launch_bounds__(256) void node_attn1_kernel(const float* __restrict__ H, const float* __restrict__ att_s,
                                                         const float* __restrict__ att_d, float* __restrict__ as_o,
                                                         float* __restrict__ ad_o, int nn) {
    __shared__ float ssm[128], dsm[128];
    int tid = threadIdx.x;
    if (tid < 128) { ssm[tid] = att_s[tid]; dsm[tid] = att_d[tid]; }
    __syncthreads();
    int id = blockIdx.x * 256 + tid;
    if (id >= nn * 4) return;
    int n = id >> 2, h = id & 3;
    const float* hp = &H[(size_t)n * 128 + h * 32];
    const float* sp = &ssm[h * 32];
    const float* dp = &dsm[h * 32];
    float s = 0.f, d = 0.f;
#pragma unroll
    for (int k = 0; k < 32; k += 4) {
        float4 v = *(const float4*)&hp[k];
        s += v.x * sp[k] + v.y * sp[k + 1] + v.z * sp[k + 2] + v.w * sp[k + 3];
        d += v.x * dp[k] + v.y * dp[k + 1] + v.z * dp[k + 2] + v.w * dp[k + 3];
    }
    as_o[id] = s;
    ad_o[id] = d;
}

// ---------------- CSR build ----------------
__global__ __launch_bounds__(256) void deg_hist_kernel(const int* __restrict__ dst, int* __restrict__ deg, int ne) {
    int e = blockIdx.x * 256 + threadIdx.x;
    if (e < ne) atomicAdd(&deg[dst[e]], 1);
}

// 3-phase multi-block exclusive scan of deg[NN] -> rowptr/cursor
__global__ __launch_bounds__(256) void scan_part_kernel(const int* __restrict__ deg, int* __restrict__ blocksum) {
    int i = blockIdx.x * 256 + threadIdx.x;
    int d = (i < NN) ? deg[i] : 0;
#pragma unroll
    for (int off = 1; off < 64; off <<= 1) d += __shfl_xor(d, off);
    __shared__ int sm[4];
    if ((threadIdx.x & 63) == 0) sm[threadIdx.x >> 6] = d;
    __syncthreads();
    if (threadIdx.x == 0) blocksum[blockIdx.x] = sm[0] + sm[1] + sm[2] + sm[3];
}

__global__ __launch_bounds__(256) void scan_block_kernel(const int* __restrict__ blocksum, int* __restrict__ blockoff) {
    __shared__ int sm[256];
    int tid = threadIdx.x;
    int v = (tid < NBLK) ? blocksum[tid] : 0;
    sm[tid] = v;
    __syncthreads();
    for (int off = 1; off < 256; off <<= 1) {
        int t = (tid >= off) ? sm[tid - off] : 0;
        __syncthreads();
        sm[tid] += t;
        __syncthreads();
    }
    if (tid < NBLK) blockoff[tid] = sm[tid] - v;  // exclusive
}

__global__ __launch_bounds__(256) void scan_final_kernel(const int* __restrict__ deg, const int* __restrict__ blockoff,
                                                         int* __restrict__ rowptr, int* __restrict__ cursor) {
    __shared__ int sm[256];
    int tid = threadIdx.x;
    int i = blockIdx.x * 256 + tid;
    int d = (i < NN) ? deg[i] : 0;
    sm[tid] = d;
    __syncthreads();
    for (int off = 1; off < 256; off <<= 1) {
        int t = (tid >= off) ? sm[tid - off] : 0;
        __syncthreads();
        sm[tid] += t;
        __syncthreads();
    }
    int excl = sm[tid] - d + blockoff[blockIdx.x];
    if (i < NN) { rowptr[i] = excl; cursor[i] = excl; }
    if (i == NN - 1) rowptr[NN] = excl + d;
}

__global__ __launch_bounds__(256) void scatter_kernel(const int* __restrict__ src, const int* __restrict__ dst,
                                                      int* __restrict__ cursor, int* __restrict__ csr_src, int ne) {
    int e = blockIdx.x * 256 + threadIdx.x;
    if (e < ne) {
        int d = dst[e];
        int pos = atomicAdd(&cursor[d], 1);
        csr_src[pos] = src[e];
    }
}

// ---------------- GAT layer 1 aggregation ----------------
// Wave per node. Lane-parallel edge phase (idx + all-4-head exp), then pairwise
// aggregation: half-wave (32 lanes x float4) per edge, 2 edges in flight.
__global__ __launch_bounds__(256) void gat1_agg_kernel(const float* __restrict__ H, const float* __restrict__ as1,
                                                       const float* __restrict__ ad1, const int* __restrict__ rowptr,
                                                       const int* __restrict__ csr_src, const float* __restrict__ bias1,
                                                       float* __restrict__ out) {
    int n = blockIdx.x * 4 + (threadIdx.x >> 6);
    int lane = threadIdx.x & 63;
    int half = lane >> 5;     // which edge of the in-flight pair
    int within = lane & 31;
    int c4 = within * 4;      // channels [c4..c4+3]
    int headc = within >> 3;  // head of this channel group
    int start = rowptr[n], end = rowptr[n + 1];

    float4 ad4 = *(const float4*)&ad1[n * 4];
    float4 as4s = *(const float4*)&as1[n * 4];
    float es0 = lrelu(as4s.x + ad4.x);
    float es1 = lrelu(as4s.y + ad4.y);
    float es2 = lrelu(as4s.z + ad4.z);
    float es3 = lrelu(as4s.w + ad4.w);

    // pass A: per-head max (self included), lane-parallel over edges
    float m0 = es0, m1 = es1, m2 = es2, m3 = es3;
    for (int base = start; base < end; base += 64) {
        int i = base + lane;
        if (i < end) {
            int s = csr_src[i];
            float4 a = *(const float4*)&as1[(size_t)s * 4];
            m0 = fmaxf(m0, lrelu(a.x + ad4.x));
            m1 = fmaxf(m1, lrelu(a.y + ad4.y));
            m2 = fmaxf(m2, lrelu(a.z + ad4.z));
            m3 = fmaxf(m3, lrelu(a.w + ad4.w));
        }
    }
#pragma unroll
    for (int off = 1; off < 64; off <<= 1) {
        m0 = fmaxf(m0, __shfl_xor(m0, off));
        m1 = fmaxf(m1, __shfl_xor(m1, off));
        m2 = fmaxf(m2, __shfl_xor(m2, off));
        m3 = fmaxf(m3, __shfl_xor(m3, off));
    }

    // self contribution: den on lane 0 only; acc on half 0 only
    float d0 = 0.f, d1 = 0.f, d2 = 0.f, d3 = 0.f;
    if (lane == 0) {
        d0 = __expf(es0 - m0); d1 = __expf(es1 - m1);
        d2 = __expf(es2 - m2); d3 = __expf(es3 - m3);
    }
    float acc0 = 0.f, acc1 = 0.f, acc2 = 0.f, acc3 = 0.f;
    {
        float msel = (headc == 0) ? m0 : (headc == 1) ? m1 : (headc == 2) ? m2 : m3;
        float esel = (headc == 0) ? es0 : (headc == 1) ? es1 : (headc == 2) ? es2 : es3;
        float pself = __expf(esel - msel);
        if (half == 0) {
            float4 hv = *(const float4*)&H[(size_t)n * 128 + c4];
            acc0 = pself * hv.x; acc1 = pself * hv.y;
            acc2 = pself * hv.z; acc3 = pself * hv.w;
        }
    }

    // pass B: lane-parallel weights, pairwise aggregation
    for (int base = start; base < end; base += 64) {
        int i = base + lane;
        int s = 0;
        float p0 = 0.f, p1 = 0.f, p2 = 0.f, p3 = 0.f;
        if (i < end) {
            s = csr_src[i];
            float4 a = *(const float4*)&as1[(size_t)s * 4];
            p0 = __expf(lrelu(a.x + ad4.x) - m0);
            p1 = __expf(lrelu(a.y + ad4.y) - m1);
            p2 = __expf(lrelu(a.z + ad4.z) - m2);
            p3 = __expf(lrelu(a.w + ad4.w) - m3);
            d0 += p0; d1 += p1; d2 += p2; d3 += p3;
        }
        int cnt = min(64, end - base);
#pragma unroll 2
        for (int j = 0; j < cnt; j += 2) {
            int jj = j + half;
            int s0 = __shfl(s, jj);
            float q0 = __shfl(p0, jj);
            float q1 = __shfl(p1, jj);
            float q2 = __shfl(p2, jj);
            float q3 = __shfl(p3, jj);
            float p = (headc == 0) ? q0 : (headc == 1) ? q1 : (headc == 2) ? q2 : q3;
            if (jj < cnt) {
                float4 hv = *(const float4*)&H[(size_t)s0 * 128 + c4];
                acc0 += p * hv.x; acc1 += p * hv.y;
                acc2 += p * hv.z; acc3 += p * hv.w;
            }
        }
    }

    // reduce den over lanes; fold edge halves of acc
#pragma unroll
    for (int off = 1; off < 64; off <<= 1) {
        d0 += __shfl_xor(d0, off);
        d1 += __shfl_xor(d1, off);
        d2 += __shfl_xor(d2, off);
        d3 += __shfl_xor(d3, off);
    }
    acc0 += __shfl_xor(acc0, 32);
    acc1 += __shfl_xor(acc1, 32);
    acc2 += __shfl_xor(acc2, 32);
    acc3 += __shfl_xor(acc3, 32);

    if (half == 0) {
        float den = (headc == 0) ? d0 : (headc == 1) ? d1 : (headc == 2) ? d2 : d3;
        float inv = 1.f / den;
        float4 bv = *(const float4*)&bias1[c4];
        float4 o;
        o.x = fmaxf(acc0 * inv + bv.x, 0.f);
        o.y = fmaxf(acc1 * inv + bv.y, 0.f);
        o.z = fmaxf(acc2 * inv + bv.z, 0.f);
        o.w = fmaxf(acc3 * inv + bv.w, 0.f);
        *(float4*)&out[(size_t)n * 128 + c4] = o;
    }
}

// ---------------- GEMM2 (N,128)@(128,16) + fused as2/ad2 epilogue ----------------
__global__ __launch_bounds__(256) void gemm2_kernel(const float* __restrict__ X, const float* __restrict__ Wp,
                                                    const float* __restrict__ hb, const float* __restrict__ atts,
                                                    const float* __restrict__ attd, float* __restrict__ H2,
                                                    float* __restrict__ as_o, float* __restrict__ ad_o) {
    __shared__ float xs[16][129];
    __shared__ float wsm[128][16];
    __shared__ float hbs[16], ats[16], atd[16];
    int tid = threadIdx.x;
    if (tid < 16) { hbs[tid] = hb[tid]; ats[tid] = atts[tid]; atd[tid] = attd[tid]; }
    for (int u = tid; u < 2048; u += 256) wsm[u >> 4][u & 15] = Wp[u];
    int r0 = blockIdx.x * 16;
    for (int u = tid; u < 2048; u += 256) {
        int row = u >> 7, cc = u & 127;
        xs[row][cc] = X[(size_t)(r0 + row) * 128 + cc];
    }
    __syncthreads();
    int r = tid >> 4, c = tid & 15;
    float acc = 0.f;
#pragma unroll 8
    for (int k = 0; k < 128; k++) acc += xs[r][k] * wsm[k][c];
    acc += hbs[c];
    H2[(size_t)(r0 + r) * 16 + c] = acc;
    float s = acc * ats[c], d = acc * atd[c];
#pragma unroll
    for (int off = 1; off < 16; off <<= 1) {
        s += __shfl_xor(s, off);
        d += __shfl_xor(d, off);
    }
    if (c == 0) { as_o[r0 + r] = s; ad_o[r0 + r] = d; }
}

// ---------------- GAT layer 2 aggregation + bias + GELU ----------------
// Wave per node; 4 edges in flight (16 lanes x 4B per edge).
__global__ __launch_bounds__(256) void gat2_agg_kernel(const float* __restrict__ H2, const float* __restrict__ as2,
                                                       const float* __restrict__ ad2, const int* __restrict__ rowptr,
                                                       const int* __restrict__ csr_src, const float* __restrict__ bias2,
                                                       float* __restrict__ out) {
    int n = blockIdx.x * 4 + (threadIdx.x >> 6);
    int lane = threadIdx.x & 63;
    int quarter = lane >> 4;
    int c = lane & 15;
    int start = rowptr[n], end = rowptr[n + 1];
    float adn = ad2[n], asn = as2[n];
    float eself = lrelu(asn + adn);

    float m = eself;
    for (int base = start; base < end; base += 64) {
        int i = base + lane;
        if (i < end) m = fmaxf(m, lrelu(as2[csr_src[i]] + adn));
    }
#pragma unroll
    for (int off = 1; off < 64; off <<= 1) m = fmaxf(m, __shfl_xor(m, off));

    float den = (lane == 0) ? __expf(eself - m) : 0.f;
    float acc = 0.f;
    if (quarter == 0) acc = __expf(eself - m) * H2[(size_t)n * 16 + c];

    for (int base = start; base < end; base += 64) {
        int i = base + lane;
        int s = 0;
        float p = 0.f;
        if (i < end) {
            s = csr_src[i];
            p = __expf(lrelu(as2[s] + adn) - m);
            den += p;
        }
        int cnt = min(64, end - base);
#pragma unroll 2
        for (int j = 0; j < cnt; j += 4) {
            int jj = j + quarter;
            int s0 = __shfl(s, jj);
            float p0 = __shfl(p, jj);
            if (jj < cnt) acc += p0 * H2[(size_t)s0 * 16 + c];
        }
    }
#pragma unroll
    for (int off = 1; off < 64; off <<= 1) den += __shfl_xor(den, off);
    acc += __shfl_xor(acc, 16);
    acc += __shfl_xor(acc, 32);

    if (quarter == 0) {
        float xo = acc / den + bias2[c];
        float t = tanhf(0.7978845608028654f * (xo + 0.044715f * xo * xo * xo));
        out[(size_t)n * 16 + c] = 0.5f * xo * (1.f + t);
    }
}

// ---------------- mean pool per graph + log_softmax ----------------
__global__ __launch_bounds__(256) void pool_lsm_kernel(const float* __restrict__ X, const int* __restrict__ batch,
                                                       int nn, float* __restrict__ out) {
    int g = blockIdx.x;
    int tid = threadIdx.x;
    int lo = 0, hi = nn;
    while (lo < hi) { int mid = (lo + hi) >> 1; if (batch[mid] < g) lo = mid + 1; else hi = mid; }
    int s = lo;
    lo = s; hi = nn;
    while (lo < hi) { int mid = (lo + hi) >> 1; if (batch[mid] < g + 1) lo = mid + 1; else hi = mid; }
    int e2 = lo;
    int c = tid & 15, grp = tid >> 4;
    float acc = 0.f;
    for (int r = s + grp; r < e2; r += 16) acc += X[(size_t)r * 16 + c];
    __shared__ float sm[256];
    sm[tid] = acc;
    __syncthreads();
    for (int off = 8; off >= 1; off >>= 1) {
        if (grp < off) sm[tid] += sm[tid + off * 16];
        __syncthreads();
    }
    if (tid < 16) {
        float cnt = (float)(e2 - s);
        float v = sm[tid] / fmaxf(cnt, 1.f);
        float mx = v;
        mx = fmaxf(mx, __shfl_xor(mx, 1));
        mx = fmaxf(mx, __shfl_xor(mx, 2));
        mx = fmaxf(mx, __shfl_xor(mx, 4));
        mx = fmaxf(mx, __shfl_xor(mx, 8));
        float ex = __expf(v - mx);
        float ssum = ex;
        ssum += __shfl_xor(ssum, 1);
        ssum += __shfl_xor(ssum, 2);
        ssum += __shfl_xor(ssum, 4);
        ssum += __shfl_xor(ssum, 8);
        out[g * 16 + tid] = v - mx - __logf(ssum);
    }
}

extern "C" void kernel_launch(void* const* d_in, const int* in_sizes, int n_in,
                              void* d_out, int out_size, void* d_ws, size_t ws_size,
                              hipStream_t stream) {
    const float* x        = (const float*)d_in[0];
    const float* W1       = (const float*)d_in[1];
    const float* att_src1 = (const float*)d_in[2];
    const float* att_dst1 = (const float*)d_in[3];
    const float* bias1    = (const float*)d_in[4];
    const float* W2       = (const float*)d_in[5];
    const float* att_src2 = (const float*)d_in[6];
    const float* att_dst2 = (const float*)d_in[7];
    const float* bias2    = (const float*)d_in[8];
    const float* bn1g     = (const float*)d_in[9];
    const float* bn1b     = (const float*)d_in[10];
    const float* bn2g     = (const float*)d_in[11];
    const float* bn2b     = (const float*)d_in[12];
    const int*   ei       = (const int*)d_in[13];
    const int*   batch    = (const int*)d_in[14];
    float* out = (float*)d_out;

    char* p = (char*)d_ws;
    auto alloc = [&](size_t bytes) -> char* {
        char* r = p;
        p += (bytes + 255) & ~(size_t)255;
        return r;
    };
    float* bnbuf   = (float*)alloc(512 * sizeof(float));
    int*   deg     = (int*)alloc(NN * sizeof(int));  // contiguous with bnbuf (zero region)
    int*   rowptr  = (int*)alloc((NN + 1) * sizeof(int));
    int*   cursor  = (int*)alloc(NN * sizeof(int));
    int*   csr_src = (int*)alloc(NE * sizeof(int));
    int*   blocksum= (int*)alloc(NBLK * sizeof(int));
    int*   blockoff= (int*)alloc(NBLK * sizeof(int));
    float* W1p     = (float*)alloc(128 * 128 * sizeof(float));
    float* h1bias  = (float*)alloc(128 * sizeof(float));
    float* h1      = (float*)alloc((size_t)NN * 128 * sizeof(float));
    float* as1     = (float*)alloc((size_t)NN * 4 * sizeof(float));
    float* ad1     = (float*)alloc((size_t)NN * 4 * sizeof(float));
    float* out1    = (float*)alloc((size_t)NN * 128 * sizeof(float));
    float* W2p     = (float*)alloc(128 * 16 * sizeof(float));
    float* h2bias  = (float*)alloc(16 * sizeof(float));
    float* h2      = (float*)alloc((size_t)NN * 16 * sizeof(float));
    float* as2     = (float*)alloc(NN * sizeof(float));
    float* ad2     = (float*)alloc(NN * sizeof(float));
    float* out2g   = (float*)alloc((size_t)NN * 16 * sizeof(float));

    float* bn1sum = bnbuf;
    float* bn1ss  = bnbuf + 128;
    float* bn2sum = bnbuf + 256;
    float* bn2ss  = bnbuf + 384;
    const int* esrc = ei;
    const int* edst = ei + NE;

    hipMemsetAsync(bnbuf, 0, 512 * sizeof(float) + NN * sizeof(int), stream);

    const float inv_n = 1.f / (float)NN;

    col_stats_kernel<<<256, 256, 0, stream>>>(x, NN, bn1sum, bn1ss);
    bn_prep_kernel<<<1, 128, 0, stream>>>(bn1sum, bn1ss, bn1g, bn1b, W1, 128, inv_n, W1p, h1bias);
    gemm1_kernel<<<(NN + 63) / 64, 256, 0, stream>>>(x, W1p, h1bias, h1, NN);
    node_attn1_kernel<<<(NN * 4 + 255) / 256, 256, 0, stream>>>(h1, att_src1, att_dst1, as1, ad1, NN);
    deg_hist_kernel<<<(NE + 255) / 256, 256, 0, stream>>>(edst, deg, NE);
    scan_part_kernel<<<NBLK, 256, 0, stream>>>(deg, blocksum);
    scan_block_kernel<<<1, 256, 0, stream>>>(blocksum, blockoff);
    scan_final_kernel<<<NBLK, 256, 0, stream>>>(deg, blockoff, rowptr, cursor);
    scatter_kernel<<<(NE + 255) / 256, 256, 0, stream>>>(esrc, edst, cursor, csr_src, NE);
    gat1_agg_kernel<<<NN / 4, 256, 0, stream>>>(h1, as1, ad1, rowptr, csr_src, bias1, out1);
    col_stats_kernel<<<256, 256, 0, stream>>>(out1, NN, bn2sum, bn2ss);
    bn_prep_kernel<<<1, 128, 0, stream>>>(bn2sum, bn2ss, bn2g, bn2b, W2, 16, inv_n, W2p, h2bias);
    gemm2_kernel<<<NN / 16, 256, 0, stream>>>(out1, W2p, h2bias, att_src2, att_dst2, h2, as2, ad2);
    gat2_agg_kernel<<<NN / 4, 256, 0, stream>>>(h2, as2, ad2, rowptr, csr_src, bias2, out2g);
    pool_lsm_kernel<<<NG, 256, 0, stream>>>(out2g, batch, NN, out);
}

// Round 6
// 416.207 us; speedup vs baseline: 1.4111x; 1.1115x over previous
//
#include <hip/hip_runtime.h>
#include <math.h>
#include <stdint.h>

#define NN 50000
#define NE 800000
#define NG 64
#define NEG_SLOPE 0.2f
#define NBLK ((NN + 255) / 256)   // 196 scan blocks

typedef unsigned short u16;
typedef __attribute__((ext_vector_type(8))) unsigned short ushort8;

__device__ __forceinline__ float lrelu(float x) { return x > 0.f ? x : NEG_SLOPE * x; }
__device__ __forceinline__ float bf2f(u16 u) { return __uint_as_float(((unsigned)u) << 16); }
__device__ __forceinline__ u16 f2bf(float f) {
    unsigned b = __float_as_uint(f);
    return (u16)((b + 0x7FFF + ((b >> 16) & 1)) >> 16);  // RNE
}

// ---------------- column stats (mean/var prep) over [nrows,128] ----------------
__global__ __launch_bounds__(256) void col_stats_kernel(const float* __restrict__ X, int nrows,
                                                        float* __restrict__ sum, float* __restrict__ ssum) {
    int tid = threadIdx.x;
    int c = tid & 127, half = tid >> 7;
    int rows_per = (nrows + gridDim.x - 1) / gridDim.x;
    int r0 = blockIdx.x * rows_per;
    int r1 = r0 + rows_per; if (r1 > nrows) r1 = nrows;
    float s = 0.f, ss = 0.f;
    for (int r = r0 + half; r < r1; r += 2) {
        float v = X[(size_t)r * 128 + c];
        s += v; ss += v * v;
    }
    __shared__ float sm1[256], sm2[256];
    sm1[tid] = s; sm2[tid] = ss;
    __syncthreads();
    if (tid < 128) {
        s = sm1[tid] + sm1[tid + 128];
        ss = sm2[tid] + sm2[tid + 128];
        atomicAdd(&sum[c], s);
        atomicAdd(&ssum[c], ss);
    }
}

// ---------------- BN fold: Wp[k][j] = a_k*W[k][j], hbias[j] = sum_k b_k*W[k][j] ----------------
__global__ __launch_bounds__(128) void bn_prep_kernel(const float* __restrict__ sum, const float* __restrict__ ssum,
                                                      const float* __restrict__ gamma, const float* __restrict__ beta,
                                                      const float* __restrict__ W, int J, float inv_n,
                                                      float* __restrict__ Wp, float* __restrict__ hb) {
    int k = threadIdx.x; // 128
    float mean = sum[k] * inv_n;
    float var = ssum[k] * inv_n - mean * mean;
    float a = gamma[k] * rsqrtf(var + 1e-5f);
    float b = beta[k] - mean * a;
    for (int j = 0; j < J; j++) Wp[k * J + j] = a * W[k * J + j];
    __shared__ float bs[128];
    bs[k] = b;
    __syncthreads();
    if (k < J) {
        float acc = 0.f;
        for (int kk = 0; kk < 128; kk++) acc += bs[kk] * W[kk * J + k];
        hb[k] = acc;
    }
}

// ---------------- GEMM1: Hb[N,128](bf16) = X @ Wp + hbias; fused as1/ad1 epilogue ----------------
__global__ __launch_bounds__(256) void gemm1_kernel(const float* __restrict__ X, const float* __restrict__ Wp,
                                                    const float* __restrict__ hbias, const float* __restrict__ atts,
                                                    const float* __restrict__ attd, u16* __restrict__ Hb,
                                                    float* __restrict__ as_o, float* __restrict__ ad_o, int nrows) {
    __shared__ float xs[64][36];    // 64 rows x 32 k-chunk, pad to 36
    __shared__ float wsm[32][128];  // k-chunk x 128 cols
    int tid = threadIdx.x;
    int ty = tid >> 4, tx = tid & 15;
    int r0 = blockIdx.x * 64;
    float acc[4][8];
#pragma unroll
    for (int i = 0; i < 4; i++)
#pragma unroll
        for (int j = 0; j < 8; j++) acc[i][j] = 0.f;

    for (int kb = 0; kb < 128; kb += 32) {
        for (int u = tid; u < 512; u += 256) {
            int row = u >> 3, c4 = u & 7;
            float4 v = make_float4(0.f, 0.f, 0.f, 0.f);
            int gr = r0 + row;
            if (gr < nrows) v = *(const float4*)&X[(size_t)gr * 128 + kb + c4 * 4];
            *(float4*)&xs[row][c4 * 4] = v;
        }
        for (int u = tid; u < 1024; u += 256) {
            int kk = u >> 5, c4 = u & 31;
            *(float4*)&wsm[kk][c4 * 4] = *(const float4*)&Wp[(size_t)(kb + kk) * 128 + c4 * 4];
        }
        __syncthreads();
#pragma unroll
        for (int k = 0; k < 32; k++) {
            float xv[4];
#pragma unroll
            for (int i = 0; i < 4; i++) xv[i] = xs[ty * 4 + i][k];
            float4 wa = *(float4*)&wsm[k][tx * 8];
            float4 wb = *(float4*)&wsm[k][tx * 8 + 4];
            float wv[8] = {wa.x, wa.y, wa.z, wa.w, wb.x, wb.y, wb.z, wb.w};
#pragma unroll
            for (int i = 0; i < 4; i++)
#pragma unroll
                for (int j = 0; j < 8; j++) acc[i][j] += xv[i] * wv[j];
        }
        __syncthreads();
    }
    float hb[8], sw[8], dw[8];
    {
        float4 t0 = *(const float4*)&hbias[tx * 8];
        float4 t1 = *(const float4*)&hbias[tx * 8 + 4];
        hb[0]=t0.x; hb[1]=t0.y; hb[2]=t0.z; hb[3]=t0.w; hb[4]=t1.x; hb[5]=t1.y; hb[6]=t1.z; hb[7]=t1.w;
        t0 = *(const float4*)&atts[tx * 8]; t1 = *(const float4*)&atts[tx * 8 + 4];
        sw[0]=t0.x; sw[1]=t0.y; sw[2]=t0.z; sw[3]=t0.w; sw[4]=t1.x; sw[5]=t1.y; sw[6]=t1.z; sw[7]=t1.w;
        t0 = *(const float4*)&attd[tx * 8]; t1 = *(const float4*)&attd[tx * 8 + 4];
        dw[0]=t0.x; dw[1]=t0.y; dw[2]=t0.z; dw[3]=t0.w; dw[4]=t1.x; dw[5]=t1.y; dw[6]=t1.z; dw[7]=t1.w;
    }
#pragma unroll
    for (int i = 0; i < 4; i++) {
        int gr = r0 + ty * 4 + i;
        float v[8];
        float sa = 0.f, da = 0.f;
#pragma unroll
        for (int j = 0; j < 8; j++) {
            v[j] = acc[i][j] + hb[j];
            sa += v[j] * sw[j];
            da += v[j] * dw[j];
        }
        // reduce over the 4-lane head group (tx&3)
        sa += __shfl_xor(sa, 1); sa += __shfl_xor(sa, 2);
        da += __shfl_xor(da, 1); da += __shfl_xor(da, 2);
        if (gr < nrows) {
            ushort8 hv;
#pragma unroll
            for (int j = 0; j < 8; j++) hv[j] = f2bf(v[j]);
            *(ushort8*)&Hb[(size_t)gr * 128 + tx * 8] = hv;
            if ((tx & 3) == 0) {
                as_o[gr * 4 + (tx >> 2)] = sa;
                ad_o[gr * 4 + (tx >> 2)] = da;
            }
        }
    }
}

// ---------------- CSR build ----------------
__global__ __launch_bounds__(256) void deg_hist_kernel(const int* __restrict__ dst, int* __restrict__ deg, int ne) {
    int e = blockIdx.x * 256 + threadIdx.x;
    if (e < ne) atomicAdd(&deg[dst[e]], 1);
}

// 3-phase multi-block exclusive scan of deg[NN] -> rowptr/cursor
__global__ __launch_bounds__(256) void scan_part_kernel(const int* __restrict__ deg, int* __restrict__ blocksum) {
    int i = blockIdx.x * 256 + threadIdx.x;
    int d = (i < NN) ? deg[i] : 0;
#pragma unroll
    for (int off = 1; off < 64; off <<= 1) d += __shfl_xor(d, off);
    __shared__ int sm[4];
    if ((threadIdx.x & 63) == 0) sm[threadIdx.x >> 6] = d;
    __syncthreads();
    if (threadIdx.x == 0) blocksum[blockIdx.x] = sm[0] + sm[1] + sm[2] + sm[3];
}

__global__ __launch_bounds__(256) void scan_block_kernel(const int* __restrict__ blocksum, int* __restrict__ blockoff) {
    __shared__ int sm[256];
    int tid = threadIdx.x;
    int v = (tid < NBLK) ? blocksum[tid] : 0;
    sm[tid] = v;
    __syncthreads();
    for (int off = 1; off < 256; off <<= 1) {
        int t = (tid >= off) ? sm[tid - off] : 0;
        __syncthreads();
        sm[tid] += t;
        __syncthreads();
    }
    if (tid < NBLK) blockoff[tid] = sm[tid] - v;  // exclusive
}

__global__ __launch_bounds__(256) void scan_final_kernel(const int* __restrict__ deg, const int* __restrict__ blockoff,
                                                         int* __restrict__ rowptr, int* __restrict__ cursor) {
    __shared__ int sm[256];
    int tid = threadIdx.x;
    int i = blockIdx.x * 256 + tid;
    int d = (i < NN) ? deg[i] : 0;
    sm[tid] = d;
    __syncthreads();
    for (int off = 1; off < 256; off <<= 1) {
        int t = (tid >= off) ? sm[tid - off] : 0;
        __syncthreads();
        sm[tid] += t;
        __syncthreads();
    }
    int excl = sm[tid] - d + blockoff[blockIdx.x];
    if (i < NN) { rowptr[i] = excl; cursor[i] = excl; }
    if (i == NN - 1) rowptr[NN] = excl + d;
}

__global__ __launch_bounds__(256) void scatter_kernel(const int* __restrict__ src, const int* __restrict__ dst,
                                                      int* __restrict__ cursor, int* __restrict__ csr_src, int ne) {
    int e = blockIdx.x * 256 + threadIdx.x;
    if (e < ne) {
        int d = dst[e];
        int pos = atomicAdd(&cursor[d], 1);
        csr_src[pos] = src[e];
    }
}

// ---------------- GAT layer 1 aggregation: single pass, no max, bf16 H ----------------
// Wave per node. Lane-parallel exp/den phase; 4 edges in flight (16 lanes x ushort8 = 256B row).
__global__ __launch_bounds__(256) void gat1_agg_kernel(const u16* __restrict__ Hb, const float* __restrict__ as1,
                                                       const float* __restrict__ ad1, const int* __restrict__ rowptr,
                                                       const int* __restrict__ csr_src, const float* __restrict__ bias1,
                                                       float* __restrict__ out) {
    int n = blockIdx.x * 4 + (threadIdx.x >> 6);
    int lane = threadIdx.x & 63;
    int quarter = lane >> 4;   // which edge of the in-flight quad
    int within = lane & 15;    // channel group: [within*8, within*8+8)
    int head = within >> 2;    // head of these channels
    int c8 = within * 8;
    int start = rowptr[n], end = rowptr[n + 1];

    float4 ad4 = *(const float4*)&ad1[n * 4];
    float4 as4 = *(const float4*)&as1[n * 4];
    float ps0 = __expf(lrelu(as4.x + ad4.x));
    float ps1 = __expf(lrelu(as4.y + ad4.y));
    float ps2 = __expf(lrelu(as4.z + ad4.z));
    float ps3 = __expf(lrelu(as4.w + ad4.w));
    float pselfh = (head == 0) ? ps0 : (head == 1) ? ps1 : (head == 2) ? ps2 : ps3;

    float acc[8];
    {   // self-loop contribution (quarter 0 only; folded later)
        ushort8 hv = *(const ushort8*)&Hb[(size_t)n * 128 + c8];
        float w = (quarter == 0) ? pselfh : 0.f;
#pragma unroll
        for (int k = 0; k < 8; k++) acc[k] = w * bf2f(hv[k]);
    }
    float d0 = 0.f, d1 = 0.f, d2 = 0.f, d3 = 0.f;

    for (int base = start; base < end; base += 64) {
        int i = base + lane;
        int s = 0;
        float p0 = 0.f, p1 = 0.f, p2 = 0.f, p3 = 0.f;
        if (i < end) {
            s = csr_src[i];
            float4 a = *(const float4*)&as1[(size_t)s * 4];
            p0 = __expf(lrelu(a.x + ad4.x));
            p1 = __expf(lrelu(a.y + ad4.y));
            p2 = __expf(lrelu(a.z + ad4.z));
            p3 = __expf(lrelu(a.w + ad4.w));
            d0 += p0; d1 += p1; d2 += p2; d3 += p3;
        }
        int cnt = min(64, end - base);
#pragma unroll 2
        for (int j = 0; j < cnt; j += 4) {
            int jj = j + quarter;
            int s0 = __shfl(s, jj);
            float q0 = __shfl(p0, jj);
            float q1 = __shfl(p1, jj);
            float q2 = __shfl(p2, jj);
            float q3 = __shfl(p3, jj);
            float pp = (head == 0) ? q0 : (head == 1) ? q1 : (head == 2) ? q2 : q3;
            if (jj < cnt) {
                ushort8 hv = *(const ushort8*)&Hb[(size_t)s0 * 128 + c8];
#pragma unroll
                for (int k = 0; k < 8; k++) acc[k] += pp * bf2f(hv[k]);
            }
        }
    }

    // reduce den across the wave
#pragma unroll
    for (int off = 1; off < 64; off <<= 1) {
        d0 += __shfl_xor(d0, off);
        d1 += __shfl_xor(d1, off);
        d2 += __shfl_xor(d2, off);
        d3 += __shfl_xor(d3, off);
    }
    float den = ((head == 0) ? d0 : (head == 1) ? d1 : (head == 2) ? d2 : d3) + pselfh;
    // fold the 4 edge-quarters
#pragma unroll
    for (int k = 0; k < 8; k++) {
        acc[k] += __shfl_xor(acc[k], 16);
        acc[k] += __shfl_xor(acc[k], 32);
    }
    if (quarter == 0) {
        float inv = 1.f / den;
        float4 b0 = *(const float4*)&bias1[c8];
        float4 b1 = *(const float4*)&bias1[c8 + 4];
        float4 o0, o1;
        o0.x = fmaxf(acc[0] * inv + b0.x, 0.f);
        o0.y = fmaxf(acc[1] * inv + b0.y, 0.f);
        o0.z = fmaxf(acc[2] * inv + b0.z, 0.f);
        o0.w = fmaxf(acc[3] * inv + b0.w, 0.f);
        o1.x = fmaxf(acc[4] * inv + b1.x, 0.f);
        o1.y = fmaxf(acc[5] * inv + b1.y, 0.f);
        o1.z = fmaxf(acc[6] * inv + b1.z, 0.f);
        o1.w = fmaxf(acc[7] * inv + b1.w, 0.f);
        *(float4*)&out[(size_t)n * 128 + c8] = o0;
        *(float4*)&out[(size_t)n * 128 + c8 + 4] = o1;
    }
}

// ---------------- GEMM2 (N,128)@(128,16) + fused as2/ad2 epilogue ----------------
__global__ __launch_bounds__(256) void gemm2_kernel(const float* __restrict__ X, const float* __restrict__ Wp,
                                                    const float* __restrict__ hb, const float* __restrict__ atts,
                                                    const float* __restrict__ attd, float* __restrict__ H2,
                                                    float* __restrict__ as_o, float* __restrict__ ad_o) {
    __shared__ float xs[16][129];
    __shared__ float wsm[128][16];
    __shared__ float hbs[16], ats[16], atd[16];
    int tid = threadIdx.x;
    if (tid < 16) { hbs[tid] = hb[tid]; ats[tid] = atts[tid]; atd[tid] = attd[tid]; }
    for (int u = tid; u < 2048; u += 256) wsm[u >> 4][u & 15] = Wp[u];
    int r0 = blockIdx.x * 16;
    for (int u = tid; u < 2048; u += 256) {
        int row = u >> 7, cc = u & 127;
        xs[row][cc] = X[(size_t)(r0 + row) * 128 + cc];
    }
    __syncthreads();
    int r = tid >> 4, c = tid & 15;
    float acc = 0.f;
#pragma unroll 8
    for (int k = 0; k < 128; k++) acc += xs[r][k] * wsm[k][c];
    acc += hbs[c];
    H2[(size_t)(r0 + r) * 16 + c] = acc;
    float s = acc * ats[c], d = acc * atd[c];
#pragma unroll
    for (int off = 1; off < 16; off <<= 1) {
        s += __shfl_xor(s, off);
        d += __shfl_xor(d, off);
    }
    if (c == 0) { as_o[r0 + r] = s; ad_o[r0 + r] = d; }
}

// ---------------- GAT layer 2 aggregation: single pass, no max; + bias + GELU ----------------
__global__ __launch_bounds__(256) void gat2_agg_kernel(const float* __restrict__ H2, const float* __restrict__ as2,
                                                       const float* __restrict__ ad2, const int* __restrict__ rowptr,
                                                       const int* __restrict__ csr_src, const float* __restrict__ bias2,
                                                       float* __restrict__ out) {
    int n = blockIdx.x * 4 + (threadIdx.x >> 6);
    int lane = threadIdx.x & 63;
    int quarter = lane >> 4;
    int c = lane & 15;
    int start = rowptr[n], end = rowptr[n + 1];
    float adn = ad2[n], asn = as2[n];
    float pself = __expf(lrelu(asn + adn));

    float acc = (quarter == 0) ? pself * H2[(size_t)n * 16 + c] : 0.f;
    float d = 0.f;

    for (int base = start; base < end; base += 64) {
        int i = base + lane;
        int s = 0;
        float p = 0.f;
        if (i < end) {
            s = csr_src[i];
            p = __expf(lrelu(as2[s] + adn));
            d += p;
        }
        int cnt = min(64, end - base);
#pragma unroll 2
        for (int j = 0; j < cnt; j += 4) {
            int jj = j + quarter;
            int s0 = __shfl(s, jj);
            float q = __shfl(p, jj);
            if (jj < cnt) acc += q * H2[(size_t)s0 * 16 + c];
        }
    }
#pragma unroll
    for (int off = 1; off < 64; off <<= 1) d += __shfl_xor(d, off);
    float den = d + pself;
    acc += __shfl_xor(acc, 16);
    acc += __shfl_xor(acc, 32);

    if (quarter == 0) {
        float xo = acc / den + bias2[c];
        float t = tanhf(0.7978845608028654f * (xo + 0.044715f * xo * xo * xo));
        out[(size_t)n * 16 + c] = 0.5f * xo * (1.f + t);
    }
}

// ---------------- mean pool per graph + log_softmax ----------------
__global__ __launch_bounds__(256) void pool_lsm_kernel(const float* __restrict__ X, const int* __restrict__ batch,
                                                       int nn, float* __restrict__ out) {
    int g = blockIdx.x;
    int tid = threadIdx.x;
    int lo = 0, hi = nn;
    while (lo < hi) { int mid = (lo + hi) >> 1; if (batch[mid] < g) lo = mid + 1; else hi = mid; }
    int s = lo;
    lo = s; hi = nn;
    while (lo < hi) { int mid = (lo + hi) >> 1; if (batch[mid] < g + 1) lo = mid + 1; else hi = mid; }
    int e2 = lo;
    int c = tid & 15, grp = tid >> 4;
    float acc = 0.f;
    for (int r = s + grp; r < e2; r += 16) acc += X[(size_t)r * 16 + c];
    __shared__ float sm[256];
    sm[tid] = acc;
    __syncthreads();
    for (int off = 8; off >= 1; off >>= 1) {
        if (grp < off) sm[tid] += sm[tid + off * 16];
        __syncthreads();
    }
    if (tid < 16) {
        float cnt = (float)(e2 - s);
        float v = sm[tid] / fmaxf(cnt, 1.f);
        float mx = v;
        mx = fmaxf(mx, __shfl_xor(mx, 1));
        mx = fmaxf(mx, __shfl_xor(mx, 2));
        mx = fmaxf(mx, __shfl_xor(mx, 4));
        mx = fmaxf(mx, __shfl_xor(mx, 8));
        float ex = __expf(v - mx);
        float ssum = ex;
        ssum += __shfl_xor(ssum, 1);
        ssum += __shfl_xor(ssum, 2);
        ssum += __shfl_xor(ssum, 4);
        ssum += __shfl_xor(ssum, 8);
        out[g * 16 + tid] = v - mx - __logf(ssum);
    }
}

extern "C" void kernel_launch(void* const* d_in, const int* in_sizes, int n_in,
                              void* d_out, int out_size, void* d_ws, size_t ws_size,
                              hipStream_t stream) {
    const float* x        = (const float*)d_in[0];
    const float* W1       = (const float*)d_in[1];
    const float* att_src1 = (const float*)d_in[2];
    const float* att_dst1 = (const float*)d_in[3];
    const float* bias1    = (const float*)d_in[4];
    const float* W2       = (const float*)d_in[5];
    const float* att_src2 = (const float*)d_in[6];
    const float* att_dst2 = (const float*)d_in[7];
    const float* bias2    = (const float*)d_in[8];
    const float* bn1g     = (const float*)d_in[9];
    const float* bn1b     = (const float*)d_in[10];
    const float* bn2g     = (const float*)d_in[11];
    const float* bn2b     = (const float*)d_in[12];
    const int*   ei       = (const int*)d_in[13];
    const int*   batch    = (const int*)d_in[14];
    float* out = (float*)d_out;

    char* p = (char*)d_ws;
    auto alloc = [&](size_t bytes) -> char* {
        char* r = p;
        p += (bytes + 255) & ~(size_t)255;
        return r;
    };
    float* bnbuf   = (float*)alloc(512 * sizeof(float));
    int*   deg     = (int*)alloc(NN * sizeof(int));  // contiguous with bnbuf (zero region)
    int*   rowptr  = (int*)alloc((NN + 1) * sizeof(int));
    int*   cursor  = (int*)alloc(NN * sizeof(int));
    int*   csr_src = (int*)alloc(NE * sizeof(int));
    int*   blocksum= (int*)alloc(NBLK * sizeof(int));
    int*   blockoff= (int*)alloc(NBLK * sizeof(int));
    float* W1p     = (float*)alloc(128 * 128 * sizeof(float));
    float* h1bias  = (float*)alloc(128 * sizeof(float));
    u16*   h1b     = (u16*)alloc((size_t)NN * 128 * sizeof(u16));   // bf16 H1
    float* as1     = (float*)alloc((size_t)NN * 4 * sizeof(float));
    float* ad1     = (float*)alloc((size_t)NN * 4 * sizeof(float));
    float* out1    = (float*)alloc((size_t)NN * 128 * sizeof(float));
    float* W2p     = (float*)alloc(128 * 16 * sizeof(float));
    float* h2bias  = (float*)alloc(16 * sizeof(float));
    float* h2      = (float*)alloc((size_t)NN * 16 * sizeof(float));
    float* as2     = (float*)alloc(NN * sizeof(float));
    float* ad2     = (float*)alloc(NN * sizeof(float));
    float* out2g   = (float*)alloc((size_t)NN * 16 * sizeof(float));

    float* bn1sum = bnbuf;
    float* bn1ss  = bnbuf + 128;
    float* bn2sum = bnbuf + 256;
    float* bn2ss  = bnbuf + 384;
    const int* esrc = ei;
    const int* edst = ei + NE;

    hipMemsetAsync(bnbuf, 0, 512 * sizeof(float) + NN * sizeof(int), stream);

    const float inv_n = 1.f / (float)NN;

    col_stats_kernel<<<256, 256, 0, stream>>>(x, NN, bn1sum, bn1ss);
    bn_prep_kernel<<<1, 128, 0, stream>>>(bn1sum, bn1ss, bn1g, bn1b, W1, 128, inv_n, W1p, h1bias);
    gemm1_kernel<<<(NN + 63) / 64, 256, 0, stream>>>(x, W1p, h1bias, att_src1, att_dst1, h1b, as1, ad1, NN);
    deg_hist_kernel<<<(NE + 255) / 256, 256, 0, stream>>>(edst, deg, NE);
    scan_part_kernel<<<NBLK, 256, 0, stream>>>(deg, blocksum);
    scan_block_kernel<<<1, 256, 0, stream>>>(blocksum, blockoff);
    scan_final_kernel<<<NBLK, 256, 0, stream>>>(deg, blockoff, rowptr, cursor);
    scatter_kernel<<<(NE + 255) / 256, 256, 0, stream>>>(esrc, edst, cursor, csr_src, NE);
    gat1_agg_kernel<<<NN / 4, 256, 0, stream>>>(h1b, as1, ad1, rowptr, csr_src, bias1, out1);
    col_stats_kernel<<<256, 256, 0, stream>>>(out1, NN, bn2sum, bn2ss);
    bn_prep_kernel<<<1, 128, 0, stream>>>(bn2sum, bn2ss, bn2g, bn2b, W2, 16, inv_n, W2p, h2bias);
    gemm2_kernel<<<NN / 16, 256, 0, stream>>>(out1, W2p, h2bias, att_src2, att_dst2, h2, as2, ad2);
    gat2_agg_kernel<<<NN / 4, 256, 0, stream>>>(h2, as2, ad2, rowptr, csr_src, bias2, out2g);
    pool_lsm_kernel<<<NG, 256, 0, stream>>>(out2g, batch, NN, out);
}

// Round 7
// 376.853 us; speedup vs baseline: 1.5584x; 1.1044x over previous
//
#include <hip/hip_runtime.h>
#include <math.h>
#include <stdint.h>

#define NN 50000
#define NE 800000
#define NG 64
#define NEG_SLOPE 0.2f
#define NBLK ((NN + 255) / 256)   // 196 scan blocks

typedef unsigned short u16;
typedef __attribute__((ext_vector_type(8))) unsigned short ushort8;
typedef __attribute__((ext_vector_type(8))) short short8v;   // MFMA bf16 A/B frag (4 VGPRs)
typedef __attribute__((ext_vector_type(4))) float f32x4;     // MFMA C/D frag

__device__ __forceinline__ float lrelu(float x) { return x > 0.f ? x : NEG_SLOPE * x; }
__device__ __forceinline__ float bf2f(u16 u) { return __uint_as_float(((unsigned)u) << 16); }
__device__ __forceinline__ u16 f2bf(float f) {
    unsigned b = __float_as_uint(f);
    return (u16)((b + 0x7FFF + ((b >> 16) & 1)) >> 16);  // RNE
}

// ---------------- column stats (mean/var prep) over [nrows,128] ----------------
__global__ __launch_bounds__(256) void col_stats_kernel(const float* __restrict__ X, int nrows,
                                                        float* __restrict__ sum, float* __restrict__ ssum) {
    int tid = threadIdx.x;
    int c = tid & 127, half = tid >> 7;
    int rows_per = (nrows + gridDim.x - 1) / gridDim.x;
    int r0 = blockIdx.x * rows_per;
    int r1 = r0 + rows_per; if (r1 > nrows) r1 = nrows;
    float s = 0.f, ss = 0.f;
    for (int r = r0 + half; r < r1; r += 2) {
        float v = X[(size_t)r * 128 + c];
        s += v; ss += v * v;
    }
    __shared__ float sm1[256], sm2[256];
    sm1[tid] = s; sm2[tid] = ss;
    __syncthreads();
    if (tid < 128) {
        s = sm1[tid] + sm1[tid + 128];
        ss = sm2[tid] + sm2[tid + 128];
        atomicAdd(&sum[c], s);
        atomicAdd(&ssum[c], ss);
    }
}

// ---------------- BN fold layer1: W1pT[j][k] = bf16(a_k*W[k][j]); hbias fp32 ----------------
__global__ __launch_bounds__(128) void bn_prep1_kernel(const float* __restrict__ sum, const float* __restrict__ ssum,
                                                       const float* __restrict__ gamma, const float* __restrict__ beta,
                                                       const float* __restrict__ W, float inv_n,
                                                       u16* __restrict__ WpT, float* __restrict__ hb) {
    int k = threadIdx.x; // 128
    float mean = sum[k] * inv_n;
    float var = ssum[k] * inv_n - mean * mean;
    float a = gamma[k] * rsqrtf(var + 1e-5f);
    float b = beta[k] - mean * a;
    for (int j = 0; j < 128; j++) WpT[j * 128 + k] = f2bf(a * W[k * 128 + j]);
    __shared__ float bs[128];
    bs[k] = b;
    __syncthreads();
    float acc = 0.f;
    for (int kk = 0; kk < 128; kk++) acc += bs[kk] * W[kk * 128 + k];
    hb[k] = acc;
}

// ---------------- BN fold layer2 (fp32, J=16) ----------------
__global__ __launch_bounds__(128) void bn_prep_kernel(const float* __restrict__ sum, const float* __restrict__ ssum,
                                                      const float* __restrict__ gamma, const float* __restrict__ beta,
                                                      const float* __restrict__ W, int J, float inv_n,
                                                      float* __restrict__ Wp, float* __restrict__ hb) {
    int k = threadIdx.x; // 128
    float mean = sum[k] * inv_n;
    float var = ssum[k] * inv_n - mean * mean;
    float a = gamma[k] * rsqrtf(var + 1e-5f);
    float b = beta[k] - mean * a;
    for (int j = 0; j < J; j++) Wp[k * J + j] = a * W[k * J + j];
    __shared__ float bs[128];
    bs[k] = b;
    __syncthreads();
    if (k < J) {
        float acc = 0.f;
        for (int kk = 0; kk < 128; kk++) acc += bs[kk] * W[kk * J + k];
        hb[k] = acc;
    }
}

// ---------------- GEMM1 via MFMA bf16: Hb = bf16(X @ W1p) + fused as1/ad1 epilogue ----------------
// Block = 4 waves = 64 rows. Wave: 16 rows x 128 cols = 8 col-tiles x 4 K-blocks of mfma 16x16x32.
// A frag: row=lane&15, k=(lane>>4)*8+i (global->reg, fp32->bf16). B frag: col=lane&15, same k,
// from LDS-staged W^T with 136-u16 pitch (uniform bank spread for ds_read_b128).
__global__ __launch_bounds__(256) void gemm1_mfma_kernel(const float* __restrict__ X, const u16* __restrict__ WpT,
                                                         const float* __restrict__ hbias, const float* __restrict__ atts,
                                                         const float* __restrict__ attd, u16* __restrict__ Hb,
                                                         float* __restrict__ as_o, float* __restrict__ ad_o) {
    __shared__ u16 wlds[128][136];   // [col][k], padded pitch
    int tid = threadIdx.x;
    for (int u = tid; u < 2048; u += 256) {    // 128 cols x 16 chunks of 8 u16
        int c = u >> 4, ch = u & 15;
        *(ushort8*)&wlds[c][ch * 8] = *(const ushort8*)&WpT[c * 128 + ch * 8];
    }
    int lane = tid & 63;
    int wv = tid >> 6;
    int cl = lane & 15;
    int kg = lane >> 4;
    int row_base = blockIdx.x * 64 + wv * 16;
    int rr = min(row_base + cl, NN - 1);       // A row (clamped; invalid rows discarded at store)

    short8v afrag[4];
#pragma unroll
    for (int kb = 0; kb < 4; kb++) {
        const float* xp = &X[(size_t)rr * 128 + kb * 32 + kg * 8];
        float4 x0 = *(const float4*)xp;
        float4 x1 = *(const float4*)(xp + 4);
        ushort8 t;
        t[0] = f2bf(x0.x); t[1] = f2bf(x0.y); t[2] = f2bf(x0.z); t[3] = f2bf(x0.w);
        t[4] = f2bf(x1.x); t[5] = f2bf(x1.y); t[6] = f2bf(x1.z); t[7] = f2bf(x1.w);
        afrag[kb] = (short8v)t;
    }
    __syncthreads();

    f32x4 acc[8];
#pragma unroll
    for (int ct = 0; ct < 8; ct++) {
        f32x4 a = {0.f, 0.f, 0.f, 0.f};
#pragma unroll
        for (int kb = 0; kb < 4; kb++) {
            ushort8 bv = *(const ushort8*)&wlds[ct * 16 + cl][kb * 32 + kg * 8];
            a = __builtin_amdgcn_mfma_f32_16x16x32_bf16(afrag[kb], (short8v)bv, a, 0, 0, 0);
        }
        acc[ct] = a;
    }

    // epilogue: +hbias, bf16 store, fused as1/ad1 (per-head dot + 16-lane reduce)
#pragma unroll
    for (int reg = 0; reg < 4; reg++) {
        int r = row_base + kg * 4 + reg;       // C/D row mapping (m89)
        bool valid = (r < NN);
        float sp[4] = {0.f, 0.f, 0.f, 0.f}, dp[4] = {0.f, 0.f, 0.f, 0.f};
#pragma unroll
        for (int ct = 0; ct < 8; ct++) {
            int c = ct * 16 + cl;
            float v = acc[ct][reg] + hbias[c];
            if (valid) Hb[(size_t)r * 128 + c] = f2bf(v);
            sp[ct >> 1] += v * atts[c];
            dp[ct >> 1] += v * attd[c];
        }
#pragma unroll
        for (int off = 1; off < 16; off <<= 1) {
#pragma unroll
            for (int h = 0; h < 4; h++) {
                sp[h] += __shfl_xor(sp[h], off);
                dp[h] += __shfl_xor(dp[h], off);
            }
        }
        if (valid) {
            if (cl < 4) as_o[r * 4 + cl] = sp[cl];
            else if (cl < 8) ad_o[r * 4 + (cl - 4)] = dp[cl - 4];
        }
    }
}

// ---------------- CSR build ----------------
__global__ __launch_bounds__(256) void deg_hist_kernel(const int* __restrict__ dst, int* __restrict__ deg, int ne) {
    int e = blockIdx.x * 256 + threadIdx.x;
    if (e < ne) atomicAdd(&deg[dst[e]], 1);
}

__global__ __launch_bounds__(256) void scan_part_kernel(const int* __restrict__ deg, int* __restrict__ blocksum) {
    int i = blockIdx.x * 256 + threadIdx.x;
    int d = (i < NN) ? deg[i] : 0;
#pragma unroll
    for (int off = 1; off < 64; off <<= 1) d += __shfl_xor(d, off);
    __shared__ int sm[4];
    if ((threadIdx.x & 63) == 0) sm[threadIdx.x >> 6] = d;
    __syncthreads();
    if (threadIdx.x == 0) blocksum[blockIdx.x] = sm[0] + sm[1] + sm[2] + sm[3];
}

__global__ __launch_bounds__(256) void scan_block_kernel(const int* __restrict__ blocksum, int* __restrict__ blockoff) {
    __shared__ int sm[256];
    int tid = threadIdx.x;
    int v = (tid < NBLK) ? blocksum[tid] : 0;
    sm[tid] = v;
    __syncthreads();
    for (int off = 1; off < 256; off <<= 1) {
        int t = (tid >= off) ? sm[tid - off] : 0;
        __syncthreads();
        sm[tid] += t;
        __syncthreads();
    }
    if (tid < NBLK) blockoff[tid] = sm[tid] - v;  // exclusive
}

__global__ __launch_bounds__(256) void scan_final_kernel(const int* __restrict__ deg, const int* __restrict__ blockoff,
                                                         int* __restrict__ rowptr, int* __restrict__ cursor) {
    __shared__ int sm[256];
    int tid = threadIdx.x;
    int i = blockIdx.x * 256 + tid;
    int d = (i < NN) ? deg[i] : 0;
    sm[tid] = d;
    __syncthreads();
    for (int off = 1; off < 256; off <<= 1) {
        int t = (tid >= off) ? sm[tid - off] : 0;
        __syncthreads();
        sm[tid] += t;
        __syncthreads();
    }
    int excl = sm[tid] - d + blockoff[blockIdx.x];
    if (i < NN) { rowptr[i] = excl; cursor[i] = excl; }
    if (i == NN - 1) rowptr[NN] = excl + d;
}

__global__ __launch_bounds__(256) void scatter_kernel(const int* __restrict__ src, const int* __restrict__ dst,
                                                      int* __restrict__ cursor, int* __restrict__ csr_src, int ne) {
    int e = blockIdx.x * 256 + threadIdx.x;
    if (e < ne) {
        int d = dst[e];
        int pos = atomicAdd(&cursor[d], 1);
        csr_src[pos] = src[e];
    }
}

// ---------------- GAT layer 1 aggregation: single pass, no max, bf16 H ----------------
__global__ __launch_bounds__(256) void gat1_agg_kernel(const u16* __restrict__ Hb, const float* __restrict__ as1,
                                                       const float* __restrict__ ad1, const int* __restrict__ rowptr,
                                                       const int* __restrict__ csr_src, const float* __restrict__ bias1,
                                                       float* __restrict__ out) {
    int n = blockIdx.x * 4 + (threadIdx.x >> 6);
    int lane = threadIdx.x & 63;
    int quarter = lane >> 4;   // which edge of the in-flight quad
    int within = lane & 15;    // channel group: [within*8, within*8+8)
    int head = within >> 2;    // head of these channels
    int c8 = within * 8;
    int start = rowptr[n], end = rowptr[n + 1];

    float4 ad4 = *(const float4*)&ad1[n * 4];
    float4 as4 = *(const float4*)&as1[n * 4];
    float ps0 = __expf(lrelu(as4.x + ad4.x));
    float ps1 = __expf(lrelu(as4.y + ad4.y));
    float ps2 = __expf(lrelu(as4.z + ad4.z));
    float ps3 = __expf(lrelu(as4.w + ad4.w));
    float pselfh = (head == 0) ? ps0 : (head == 1) ? ps1 : (head == 2) ? ps2 : ps3;

    float acc[8];
    {   // self-loop contribution (quarter 0 only; folded later)
        ushort8 hv = *(const ushort8*)&Hb[(size_t)n * 128 + c8];
        float w = (quarter == 0) ? pselfh : 0.f;
#pragma unroll
        for (int k = 0; k < 8; k++) acc[k] = w * bf2f(hv[k]);
    }
    float d0 = 0.f, d1 = 0.f, d2 = 0.f, d3 = 0.f;

    for (int base = start; base < end; base += 64) {
        int i = base + lane;
        int s = 0;
        float p0 = 0.f, p1 = 0.f, p2 = 0.f, p3 = 0.f;
        if (i < end) {
            s = csr_src[i];
            float4 a = *(const float4*)&as1[(size_t)s * 4];
            p0 = __expf(lrelu(a.x + ad4.x));
            p1 = __expf(lrelu(a.y + ad4.y));
            p2 = __expf(lrelu(a.z + ad4.z));
            p3 = __expf(lrelu(a.w + ad4.w));
            d0 += p0; d1 += p1; d2 += p2; d3 += p3;
        }
        int cnt = min(64, end - base);
#pragma unroll 2
        for (int j = 0; j < cnt; j += 4) {
            int jj = j + quarter;
            int s0 = __shfl(s, jj);
            float q0 = __shfl(p0, jj);
            float q1 = __shfl(p1, jj);
            float q2 = __shfl(p2, jj);
            float q3 = __shfl(p3, jj);
            float pp = (head == 0) ? q0 : (head == 1) ? q1 : (head == 2) ? q2 : q3;
            if (jj < cnt) {
                ushort8 hv = *(const ushort8*)&Hb[(size_t)s0 * 128 + c8];
#pragma unroll
                for (int k = 0; k < 8; k++) acc[k] += pp * bf2f(hv[k]);
            }
        }
    }

#pragma unroll
    for (int off = 1; off < 64; off <<= 1) {
        d0 += __shfl_xor(d0, off);
        d1 += __shfl_xor(d1, off);
        d2 += __shfl_xor(d2, off);
        d3 += __shfl_xor(d3, off);
    }
    float den = ((head == 0) ? d0 : (head == 1) ? d1 : (head == 2) ? d2 : d3) + pselfh;
#pragma unroll
    for (int k = 0; k < 8; k++) {
        acc[k] += __shfl_xor(acc[k], 16);
        acc[k] += __shfl_xor(acc[k], 32);
    }
    if (quarter == 0) {
        float inv = 1.f / den;
        float4 b0 = *(const float4*)&bias1[c8];
        float4 b1 = *(const float4*)&bias1[c8 + 4];
        float4 o0, o1;
        o0.x = fmaxf(acc[0] * inv + b0.x, 0.f);
        o0.y = fmaxf(acc[1] * inv + b0.y, 0.f);
        o0.z = fmaxf(acc[2] * inv + b0.z, 0.f);
        o0.w = fmaxf(acc[3] * inv + b0.w, 0.f);
        o1.x = fmaxf(acc[4] * inv + b1.x, 0.f);
        o1.y = fmaxf(acc[5] * inv + b1.y, 0.f);
        o1.z = fmaxf(acc[6] * inv + b1.z, 0.f);
        o1.w = fmaxf(acc[7] * inv + b1.w, 0.f);
        *(float4*)&out[(size_t)n * 128 + c8] = o0;
        *(float4*)&out[(size_t)n * 128 + c8 + 4] = o1;
    }
}

// ---------------- GEMM2 (N,128)@(128,16) + fused as2/ad2 epilogue ----------------
__global__ __launch_bounds__(256) void gemm2_kernel(const float* __restrict__ X, const float* __restrict__ Wp,
                                                    const float* __restrict__ hb, const float* __restrict__ atts,
                                                    const float* __restrict__ attd, float* __restrict__ H2,
                                                    float* __restrict__ as_o, float* __restrict__ ad_o) {
    __shared__ float xs[16][129];
    __shared__ float wsm[128][16];
    __shared__ float hbs[16], ats[16], atd[16];
    int tid = threadIdx.x;
    if (tid < 16) { hbs[tid] = hb[tid]; ats[tid] = atts[tid]; atd[tid] = attd[tid]; }
    for (int u = tid; u < 2048; u += 256) wsm[u >> 4][u & 15] = Wp[u];
    int r0 = blockIdx.x * 16;
    for (int u = tid; u < 2048; u += 256) {
        int row = u >> 7, cc = u & 127;
        xs[row][cc] = X[(size_t)(r0 + row) * 128 + cc];
    }
    __syncthreads();
    int r = tid >> 4, c = tid & 15;
    float acc = 0.f;
#pragma unroll 8
    for (int k = 0; k < 128; k++) acc += xs[r][k] * wsm[k][c];
    acc += hbs[c];
    H2[(size_t)(r0 + r) * 16 + c] = acc;
    float s = acc * ats[c], d = acc * atd[c];
#pragma unroll
    for (int off = 1; off < 16; off <<= 1) {
        s += __shfl_xor(s, off);
        d += __shfl_xor(d, off);
    }
    if (c == 0) { as_o[r0 + r] = s; ad_o[r0 + r] = d; }
}

// ---------------- GAT layer 2 aggregation: single pass, no max; + bias + GELU ----------------
__global__ __launch_bounds__(256) void gat2_agg_kernel(const float* __restrict__ H2, const float* __restrict__ as2,
                                                       const float* __restrict__ ad2, const int* __restrict__ rowptr,
                                                       const int* __restrict__ csr_src, const float* __restrict__ bias2,
                                                       float* __restrict__ out) {
    int n = blockIdx.x * 4 + (threadIdx.x >> 6);
    int lane = threadIdx.x & 63;
    int quarter = lane >> 4;
    int c = lane & 15;
    int start = rowptr[n], end = rowptr[n + 1];
    float adn = ad2[n], asn = as2[n];
    float pself = __expf(lrelu(asn + adn));

    float acc = (quarter == 0) ? pself * H2[(size_t)n * 16 + c] : 0.f;
    float d = 0.f;

    for (int base = start; base < end; base += 64) {
        int i = base + lane;
        int s = 0;
        float p = 0.f;
        if (i < end) {
            s = csr_src[i];
            p = __expf(lrelu(as2[s] + adn));
            d += p;
        }
        int cnt = min(64, end - base);
#pragma unroll 2
        for (int j = 0; j < cnt; j += 4) {
            int jj = j + quarter;
            int s0 = __shfl(s, jj);
            float q = __shfl(p, jj);
            if (jj < cnt) acc += q * H2[(size_t)s0 * 16 + c];
        }
    }
#pragma unroll
    for (int off = 1; off < 64; off <<= 1) d += __shfl_xor(d, off);
    float den = d + pself;
    acc += __shfl_xor(acc, 16);
    acc += __shfl_xor(acc, 32);

    if (quarter == 0) {
        float xo = acc / den + bias2[c];
        float t = tanhf(0.7978845608028654f * (xo + 0.044715f * xo * xo * xo));
        out[(size_t)n * 16 + c] = 0.5f * xo * (1.f + t);
    }
}

// ---------------- mean pool per graph + log_softmax ----------------
__global__ __launch_bounds__(256) void pool_lsm_kernel(const float* __restrict__ X, const int* __restrict__ batch,
                                                       int nn, float* __restrict__ out) {
    int g = blockIdx.x;
    int tid = threadIdx.x;
    int lo = 0, hi = nn;
    while (lo < hi) { int mid = (lo + hi) >> 1; if (batch[mid] < g) lo = mid + 1; else hi = mid; }
    int s = lo;
    lo = s; hi = nn;
    while (lo < hi) { int mid = (lo + hi) >> 1; if (batch[mid] < g + 1) lo = mid + 1; else hi = mid; }
    int e2 = lo;
    int c = tid & 15, grp = tid >> 4;
    float acc = 0.f;
    for (int r = s + grp; r < e2; r += 16) acc += X[(size_t)r * 16 + c];
    __shared__ float sm[256];
    sm[tid] = acc;
    __syncthreads();
    for (int off = 8; off >= 1; off >>= 1) {
        if (grp < off) sm[tid] += sm[tid + off * 16];
        __syncthreads();
    }
    if (tid < 16) {
        float cnt = (float)(e2 - s);
        float v = sm[tid] / fmaxf(cnt, 1.f);
        float mx = v;
        mx = fmaxf(mx, __shfl_xor(mx, 1));
        mx = fmaxf(mx, __shfl_xor(mx, 2));
        mx = fmaxf(mx, __shfl_xor(mx, 4));
        mx = fmaxf(mx, __shfl_xor(mx, 8));
        float ex = __expf(v - mx);
        float ssum = ex;
        ssum += __shfl_xor(ssum, 1);
        ssum += __shfl_xor(ssum, 2);
        ssum += __shfl_xor(ssum, 4);
        ssum += __shfl_xor(ssum, 8);
        out[g * 16 + tid] = v - mx - __logf(ssum);
    }
}

extern "C" void kernel_launch(void* const* d_in, const int* in_sizes, int n_in,
                              void* d_out, int out_size, void* d_ws, size_t ws_size,
                              hipStream_t stream) {
    const float* x        = (const float*)d_in[0];
    const float* W1       = (const float*)d_in[1];
    const float* att_src1 = (const float*)d_in[2];
    const float* att_dst1 = (const float*)d_in[3];
    const float* bias1    = (const float*)d_in[4];
    const float* W2       = (const float*)d_in[5];
    const float* att_src2 = (const float*)d_in[6];
    const float* att_dst2 = (const float*)d_in[7];
    const float* bias2    = (const float*)d_in[8];
    const float* bn1g     = (const float*)d_in[9];
    const float* bn1b     = (const float*)d_in[10];
    const float* bn2g     = (const float*)d_in[11];
    const float* bn2b     = (const float*)d_in[12];
    const int*   ei       = (const int*)d_in[13];
    const int*   batch    = (const int*)d_in[14];
    float* out = (float*)d_out;

    char* p = (char*)d_ws;
    auto alloc = [&](size_t bytes) -> char* {
        char* r = p;
        p += (bytes + 255) & ~(size_t)255;
        return r;
    };
    float* bnbuf   = (float*)alloc(512 * sizeof(float));
    int*   deg     = (int*)alloc(NN * sizeof(int));  // contiguous with bnbuf (zero region)
    int*   rowptr  = (int*)alloc((NN + 1) * sizeof(int));
    int*   cursor  = (int*)alloc(NN * sizeof(int));
    int*   csr_src = (int*)alloc(NE * sizeof(int));
    int*   blocksum= (int*)alloc(NBLK * sizeof(int));
    int*   blockoff= (int*)alloc(NBLK * sizeof(int));
    u16*   W1pT    = (u16*)alloc(128 * 128 * sizeof(u16));   // bf16 W1 (BN-folded, transposed)
    float* h1bias  = (float*)alloc(128 * sizeof(float));
    u16*   h1b     = (u16*)alloc((size_t)NN * 128 * sizeof(u16));   // bf16 H1
    float* as1     = (float*)alloc((size_t)NN * 4 * sizeof(float));
    float* ad1     = (float*)alloc((size_t)NN * 4 * sizeof(float));
    float* out1    = (float*)alloc((size_t)NN * 128 * sizeof(float));
    float* W2p     = (float*)alloc(128 * 16 * sizeof(float));
    float* h2bias  = (float*)alloc(16 * sizeof(float));
    float* h2      = (float*)alloc((size_t)NN * 16 * sizeof(float));
    float* as2     = (float*)alloc(NN * sizeof(float));
    float* ad2     = (float*)alloc(NN * sizeof(float));
    float* out2g   = (float*)alloc((size_t)NN * 16 * sizeof(float));

    float* bn1sum = bnbuf;
    float* bn1ss  = bnbuf + 128;
    float* bn2sum = bnbuf + 256;
    float* bn2ss  = bnbuf + 384;
    const int* esrc = ei;
    const int* edst = ei + NE;

    hipMemsetAsync(bnbuf, 0, 512 * sizeof(float) + NN * sizeof(int), stream);

    const float inv_n = 1.f / (float)NN;

    col_stats_kernel<<<256, 256, 0, stream>>>(x, NN, bn1sum, bn1ss);
    bn_prep1_kernel<<<1, 128, 0, stream>>>(bn1sum, bn1ss, bn1g, bn1b, W1, inv_n, W1pT, h1bias);
    gemm1_mfma_kernel<<<(NN + 63) / 64, 256, 0, stream>>>(x, W1pT, h1bias, att_src1, att_dst1, h1b, as1, ad1);
    deg_hist_kernel<<<(NE + 255) / 256, 256, 0, stream>>>(edst, deg, NE);
    scan_part_kernel<<<NBLK, 256, 0, stream>>>(deg, blocksum);
    scan_block_kernel<<<1, 256, 0, stream>>>(blocksum, blockoff);
    scan_final_kernel<<<NBLK, 256, 0, stream>>>(deg, blockoff, rowptr, cursor);
    scatter_kernel<<<(NE + 255) / 256, 256, 0, stream>>>(esrc, edst, cursor, csr_src, NE);
    gat1_agg_kernel<<<NN / 4, 256, 0, stream>>>(h1b, as1, ad1, rowptr, csr_src, bias1, out1);
    col_stats_kernel<<<256, 256, 0, stream>>>(out1, NN, bn2sum, bn2ss);
    bn_prep_kernel<<<1, 128, 0, stream>>>(bn2sum, bn2ss, bn2g, bn2b, W2, 16, inv_n, W2p, h2bias);
    gemm2_kernel<<<NN / 16, 256, 0, stream>>>(out1, W2p, h2bias, att_src2, att_dst2, h2, as2, ad2);
    gat2_agg_kernel<<<NN / 4, 256, 0, stream>>>(h2, as2, ad2, rowptr, csr_src, bias2, out2g);
    pool_lsm_kernel<<<NG, 256, 0, stream>>>(out2g, batch, NN, out);
}

// Round 8
// 351.864 us; speedup vs baseline: 1.6691x; 1.0710x over previous
//
#include <hip/hip_runtime.h>
#include <math.h>
#include <stdint.h>

#define NN 50000
#define NE 800000
#define NG 64
#define NEG_SLOPE 0.2f
#define NBLK ((NN + 255) / 256)   // 196 scan blocks
#define BSH 8
#define NBUCK ((NN + 255) >> 8)   // 196 dst-buckets (256 nodes each)

typedef unsigned short u16;
typedef __attribute__((ext_vector_type(8))) unsigned short ushort8;
typedef __attribute__((ext_vector_type(8))) short short8v;   // MFMA bf16 A/B frag (4 VGPRs)
typedef __attribute__((ext_vector_type(4))) float f32x4;     // MFMA C/D frag

__device__ __forceinline__ float lrelu(float x) { return x > 0.f ? x : NEG_SLOPE * x; }
__device__ __forceinline__ float bf2f(u16 u) { return __uint_as_float(((unsigned)u) << 16); }
__device__ __forceinline__ u16 f2bf(float f) {
    unsigned b = __float_as_uint(f);
    return (u16)((b + 0x7FFF + ((b >> 16) & 1)) >> 16);  // RNE
}

// ---------------- column stats (mean/var prep) over [nrows,128] ----------------
__global__ __launch_bounds__(256) void col_stats_kernel(const float* __restrict__ X, int nrows,
                                                        float* __restrict__ sum, float* __restrict__ ssum) {
    int tid = threadIdx.x;
    int c = tid & 127, half = tid >> 7;
    int rows_per = (nrows + gridDim.x - 1) / gridDim.x;
    int r0 = blockIdx.x * rows_per;
    int r1 = r0 + rows_per; if (r1 > nrows) r1 = nrows;
    float s = 0.f, ss = 0.f;
    for (int r = r0 + half; r < r1; r += 2) {
        float v = X[(size_t)r * 128 + c];
        s += v; ss += v * v;
    }
    __shared__ float sm1[256], sm2[256];
    sm1[tid] = s; sm2[tid] = ss;
    __syncthreads();
    if (tid < 128) {
        s = sm1[tid] + sm1[tid + 128];
        ss = sm2[tid] + sm2[tid + 128];
        atomicAdd(&sum[c], s);
        atomicAdd(&ssum[c], ss);
    }
}

// ---------------- BN fold layer1: W1pT[j][k] = bf16(a_k*W[k][j]); hbias fp32 ----------------
__global__ __launch_bounds__(128) void bn_prep1_kernel(const float* __restrict__ sum, const float* __restrict__ ssum,
                                                       const float* __restrict__ gamma, const float* __restrict__ beta,
                                                       const float* __restrict__ W, float inv_n,
                                                       u16* __restrict__ WpT, float* __restrict__ hb) {
    int k = threadIdx.x; // 128
    float mean = sum[k] * inv_n;
    float var = ssum[k] * inv_n - mean * mean;
    float a = gamma[k] * rsqrtf(var + 1e-5f);
    float b = beta[k] - mean * a;
    for (int j = 0; j < 128; j++) WpT[j * 128 + k] = f2bf(a * W[k * 128 + j]);
    __shared__ float bs[128];
    bs[k] = b;
    __syncthreads();
    float acc = 0.f;
    for (int kk = 0; kk < 128; kk++) acc += bs[kk] * W[kk * 128 + k];
    hb[k] = acc;
}

// ---------------- BN fold layer2 (fp32, J=16) ----------------
__global__ __launch_bounds__(128) void bn_prep_kernel(const float* __restrict__ sum, const float* __restrict__ ssum,
                                                      const float* __restrict__ gamma, const float* __restrict__ beta,
                                                      const float* __restrict__ W, int J, float inv_n,
                                                      float* __restrict__ Wp, float* __restrict__ hb) {
    int k = threadIdx.x; // 128
    float mean = sum[k] * inv_n;
    float var = ssum[k] * inv_n - mean * mean;
    float a = gamma[k] * rsqrtf(var + 1e-5f);
    float b = beta[k] - mean * a;
    for (int j = 0; j < J; j++) Wp[k * J + j] = a * W[k * J + j];
    __shared__ float bs[128];
    bs[k] = b;
    __syncthreads();
    if (k < J) {
        float acc = 0.f;
        for (int kk = 0; kk < 128; kk++) acc += bs[kk] * W[kk * J + k];
        hb[k] = acc;
    }
}

// ---------------- GEMM1 via MFMA bf16: Hb = bf16(X @ W1p) + fused as1/ad1 epilogue ----------------
__global__ __launch_bounds__(256) void gemm1_mfma_kernel(const float* __restrict__ X, const u16* __restrict__ WpT,
                                                         const float* __restrict__ hbias, const float* __restrict__ atts,
                                                         const float* __restrict__ attd, u16* __restrict__ Hb,
                                                         float* __restrict__ as_o, float* __restrict__ ad_o) {
    __shared__ u16 wlds[128][136];   // [col][k], padded pitch
    int tid = threadIdx.x;
    for (int u = tid; u < 2048; u += 256) {    // 128 cols x 16 chunks of 8 u16
        int c = u >> 4, ch = u & 15;
        *(ushort8*)&wlds[c][ch * 8] = *(const ushort8*)&WpT[c * 128 + ch * 8];
    }
    int lane = tid & 63;
    int wv = tid >> 6;
    int cl = lane & 15;
    int kg = lane >> 4;
    int row_base = blockIdx.x * 64 + wv * 16;
    int rr = min(row_base + cl, NN - 1);       // A row (clamped; invalid rows discarded at store)

    short8v afrag[4];
#pragma unroll
    for (int kb = 0; kb < 4; kb++) {
        const float* xp = &X[(size_t)rr * 128 + kb * 32 + kg * 8];
        float4 x0 = *(const float4*)xp;
        float4 x1 = *(const float4*)(xp + 4);
        ushort8 t;
        t[0] = f2bf(x0.x); t[1] = f2bf(x0.y); t[2] = f2bf(x0.z); t[3] = f2bf(x0.w);
        t[4] = f2bf(x1.x); t[5] = f2bf(x1.y); t[6] = f2bf(x1.z); t[7] = f2bf(x1.w);
        afrag[kb] = (short8v)t;
    }
    __syncthreads();

    f32x4 acc[8];
#pragma unroll
    for (int ct = 0; ct < 8; ct++) {
        f32x4 a = {0.f, 0.f, 0.f, 0.f};
#pragma unroll
        for (int kb = 0; kb < 4; kb++) {
            ushort8 bv = *(const ushort8*)&wlds[ct * 16 + cl][kb * 32 + kg * 8];
            a = __builtin_amdgcn_mfma_f32_16x16x32_bf16(afrag[kb], (short8v)bv, a, 0, 0, 0);
        }
        acc[ct] = a;
    }

    // epilogue: +hbias, bf16 store, fused as1/ad1 (per-head dot + 16-lane reduce)
#pragma unroll
    for (int reg = 0; reg < 4; reg++) {
        int r = row_base + kg * 4 + reg;       // C/D row mapping (m89)
        bool valid = (r < NN);
        float sp[4] = {0.f, 0.f, 0.f, 0.f}, dp[4] = {0.f, 0.f, 0.f, 0.f};
#pragma unroll
        for (int ct = 0; ct < 8; ct++) {
            int c = ct * 16 + cl;
            float v = acc[ct][reg] + hbias[c];
            if (valid) Hb[(size_t)r * 128 + c] = f2bf(v);
            sp[ct >> 1] += v * atts[c];
            dp[ct >> 1] += v * attd[c];
        }
#pragma unroll
        for (int off = 1; off < 16; off <<= 1) {
#pragma unroll
            for (int h = 0; h < 4; h++) {
                sp[h] += __shfl_xor(sp[h], off);
                dp[h] += __shfl_xor(dp[h], off);
            }
        }
        if (valid) {
            if (cl < 4) as_o[r * 4 + cl] = sp[cl];
            else if (cl < 8) ad_o[r * 4 + (cl - 4)] = dp[cl - 4];
        }
    }
}

// ---------------- CSR build ----------------
__global__ __launch_bounds__(256) void deg_hist_kernel(const int* __restrict__ dst, int* __restrict__ deg, int ne) {
    int e = blockIdx.x * 256 + threadIdx.x;
    if (e < ne) atomicAdd(&deg[dst[e]], 1);
}

__global__ __launch_bounds__(256) void scan_part_kernel(const int* __restrict__ deg, int* __restrict__ blocksum) {
    int i = blockIdx.x * 256 + threadIdx.x;
    int d = (i < NN) ? deg[i] : 0;
#pragma unroll
    for (int off = 1; off < 64; off <<= 1) d += __shfl_xor(d, off);
    __shared__ int sm[4];
    if ((threadIdx.x & 63) == 0) sm[threadIdx.x >> 6] = d;
    __syncthreads();
    if (threadIdx.x == 0) blocksum[blockIdx.x] = sm[0] + sm[1] + sm[2] + sm[3];
}

__global__ __launch_bounds__(256) void scan_block_kernel(const int* __restrict__ blocksum, int* __restrict__ blockoff) {
    __shared__ int sm[256];
    int tid = threadIdx.x;
    int v = (tid < NBLK) ? blocksum[tid] : 0;
    sm[tid] = v;
    __syncthreads();
    for (int off = 1; off < 256; off <<= 1) {
        int t = (tid >= off) ? sm[tid - off] : 0;
        __syncthreads();
        sm[tid] += t;
        __syncthreads();
    }
    if (tid < NBLK) blockoff[tid] = sm[tid] - v;  // exclusive
}

// also seeds per-bucket cursors (bucket = 256 consecutive nodes, aligned with scan blocks)
__global__ __launch_bounds__(256) void scan_final_kernel(const int* __restrict__ deg, const int* __restrict__ blockoff,
                                                         int* __restrict__ rowptr, int* __restrict__ bcur) {
    __shared__ int sm[256];
    int tid = threadIdx.x;
    int i = blockIdx.x * 256 + tid;
    int d = (i < NN) ? deg[i] : 0;
    sm[tid] = d;
    __syncthreads();
    for (int off = 1; off < 256; off <<= 1) {
        int t = (tid >= off) ? sm[tid - off] : 0;
        __syncthreads();
        sm[tid] += t;
        __syncthreads();
    }
    int excl = sm[tid] - d + blockoff[blockIdx.x];
    if (i < NN) {
        rowptr[i] = excl;
        if ((i & 255) == 0) bcur[i >> BSH] = excl;
    }
    if (i == NN - 1) rowptr[NN] = excl + d;
}

// ---------------- partition: bucket-ordered (src,dst) pairs, write-local ----------------
__global__ __launch_bounds__(256) void partition_kernel(const int* __restrict__ esrc, const int* __restrict__ edst,
                                                        int* __restrict__ bcur, int2* __restrict__ ebuf) {
    __shared__ int hist[NBUCK];
    __shared__ int cur[NBUCK];
    int tid = threadIdx.x;
    for (int b = tid; b < NBUCK; b += 256) hist[b] = 0;
    __syncthreads();
    int epb = (NE + gridDim.x - 1) / gridDim.x;
    int e0 = blockIdx.x * epb;
    int e1 = min(e0 + epb, NE);
    for (int e = e0 + tid; e < e1; e += 256)
        atomicAdd(&hist[edst[e] >> BSH], 1);
    __syncthreads();
    for (int b = tid; b < NBUCK; b += 256) {
        int h = hist[b];
        cur[b] = h ? atomicAdd(&bcur[b], h) : 0;
    }
    __syncthreads();
    for (int e = e0 + tid; e < e1; e += 256) {
        int s = esrc[e], d = edst[e];
        int pos = atomicAdd(&cur[d >> BSH], 1);
        ebuf[pos] = make_int2(s, d);
    }
}

// ---------------- fine scatter within each bucket (LDS cursors, 16KB write window) ----------------
__global__ __launch_bounds__(256) void fine_scatter_kernel(const int2* __restrict__ ebuf, const int* __restrict__ rowptr,
                                                           int* __restrict__ csr_src) {
    __shared__ int lcur[256];
    int b = blockIdx.x;
    int n0 = b << BSH;
    int n1 = min(n0 + 256, NN);
    int tid = threadIdx.x;
    if (n0 + tid < n1) lcur[tid] = rowptr[n0 + tid];
    __syncthreads();
    int e0 = rowptr[n0], e1 = rowptr[n1];
    for (int e = e0 + tid; e < e1; e += 256) {
        int2 p = ebuf[e];
        int pos = atomicAdd(&lcur[p.y - n0], 1);
        csr_src[pos] = p.x;
    }
}

// ---------------- GAT layer 1 aggregation: single pass, no max, bf16 H ----------------
__global__ __launch_bounds__(256) void gat1_agg_kernel(const u16* __restrict__ Hb, const float* __restrict__ as1,
                                                       const float* __restrict__ ad1, const int* __restrict__ rowptr,
                                                       const int* __restrict__ csr_src, const float* __restrict__ bias1,
                                                       float* __restrict__ out) {
    int n = blockIdx.x * 4 + (threadIdx.x >> 6);
    int lane = threadIdx.x & 63;
    int quarter = lane >> 4;   // which edge of the in-flight quad
    int within = lane & 15;    // channel group: [within*8, within*8+8)
    int head = within >> 2;    // head of these channels
    int c8 = within * 8;
    int start = rowptr[n], end = rowptr[n + 1];

    float4 ad4 = *(const float4*)&ad1[n * 4];
    float4 as4 = *(const float4*)&as1[n * 4];
    float ps0 = __expf(lrelu(as4.x + ad4.x));
    float ps1 = __expf(lrelu(as4.y + ad4.y));
    float ps2 = __expf(lrelu(as4.z + ad4.z));
    float ps3 = __expf(lrelu(as4.w + ad4.w));
    float pselfh = (head == 0) ? ps0 : (head == 1) ? ps1 : (head == 2) ? ps2 : ps3;

    float acc[8];
    {   // self-loop contribution (quarter 0 only; folded later)
        ushort8 hv = *(const ushort8*)&Hb[(size_t)n * 128 + c8];
        float w = (quarter == 0) ? pselfh : 0.f;
#pragma unroll
        for (int k = 0; k < 8; k++) acc[k] = w * bf2f(hv[k]);
    }
    float d0 = 0.f, d1 = 0.f, d2 = 0.f, d3 = 0.f;

    for (int base = start; base < end; base += 64) {
        int i = base + lane;
        int s = 0;
        float p0 = 0.f, p1 = 0.f, p2 = 0.f, p3 = 0.f;
        if (i < end) {
            s = csr_src[i];
            float4 a = *(const float4*)&as1[(size_t)s * 4];
            p0 = __expf(lrelu(a.x + ad4.x));
            p1 = __expf(lrelu(a.y + ad4.y));
            p2 = __expf(lrelu(a.z + ad4.z));
            p3 = __expf(lrelu(a.w + ad4.w));
            d0 += p0; d1 += p1; d2 += p2; d3 += p3;
        }
        int cnt = min(64, end - base);
#pragma unroll 2
        for (int j = 0; j < cnt; j += 4) {
            int jj = j + quarter;
            int s0 = __shfl(s, jj);
            float q0 = __shfl(p0, jj);
            float q1 = __shfl(p1, jj);
            float q2 = __shfl(p2, jj);
            float q3 = __shfl(p3, jj);
            float pp = (head == 0) ? q0 : (head == 1) ? q1 : (head == 2) ? q2 : q3;
            if (jj < cnt) {
                ushort8 hv = *(const ushort8*)&Hb[(size_t)s0 * 128 + c8];
#pragma unroll
                for (int k = 0; k < 8; k++) acc[k] += pp * bf2f(hv[k]);
            }
        }
    }

#pragma unroll
    for (int off = 1; off < 64; off <<= 1) {
        d0 += __shfl_xor(d0, off);
        d1 += __shfl_xor(d1, off);
        d2 += __shfl_xor(d2, off);
        d3 += __shfl_xor(d3, off);
    }
    float den = ((head == 0) ? d0 : (head == 1) ? d1 : (head == 2) ? d2 : d3) + pselfh;
#pragma unroll
    for (int k = 0; k < 8; k++) {
        acc[k] += __shfl_xor(acc[k], 16);
        acc[k] += __shfl_xor(acc[k], 32);
    }
    if (quarter == 0) {
        float inv = 1.f / den;
        float4 b0 = *(const float4*)&bias1[c8];
        float4 b1 = *(const float4*)&bias1[c8 + 4];
        float4 o0, o1;
        o0.x = fmaxf(acc[0] * inv + b0.x, 0.f);
        o0.y = fmaxf(acc[1] * inv + b0.y, 0.f);
        o0.z = fmaxf(acc[2] * inv + b0.z, 0.f);
        o0.w = fmaxf(acc[3] * inv + b0.w, 0.f);
        o1.x = fmaxf(acc[4] * inv + b1.x, 0.f);
        o1.y = fmaxf(acc[5] * inv + b1.y, 0.f);
        o1.z = fmaxf(acc[6] * inv + b1.z, 0.f);
        o1.w = fmaxf(acc[7] * inv + b1.w, 0.f);
        *(float4*)&out[(size_t)n * 128 + c8] = o0;
        *(float4*)&out[(size_t)n * 128 + c8 + 4] = o1;
    }
}

// ---------------- GEMM2 (N,128)@(128,16) + fused as2/ad2 epilogue ----------------
__global__ __launch_bounds__(256) void gemm2_kernel(const float* __restrict__ X, const float* __restrict__ Wp,
                                                    const float* __restrict__ hb, const float* __restrict__ atts,
                                                    const float* __restrict__ attd, float* __restrict__ H2,
                                                    float* __restrict__ as_o, float* __restrict__ ad_o) {
    __shared__ float xs[16][129];
    __shared__ float wsm[128][16];
    __shared__ float hbs[16], ats[16], atd[16];
    int tid = threadIdx.x;
    if (tid < 16) { hbs[tid] = hb[tid]; ats[tid] = atts[tid]; atd[tid] = attd[tid]; }
    for (int u = tid; u < 2048; u += 256) wsm[u >> 4][u & 15] = Wp[u];
    int r0 = blockIdx.x * 16;
    for (int u = tid; u < 2048; u += 256) {
        int row = u >> 7, cc = u & 127;
        xs[row][cc] = X[(size_t)(r0 + row) * 128 + cc];
    }
    __syncthreads();
    int r = tid >> 4, c = tid & 15;
    float acc = 0.f;
#pragma unroll 8
    for (int k = 0; k < 128; k++) acc += xs[r][k] * wsm[k][c];
    acc += hbs[c];
    H2[(size_t)(r0 + r) * 16 + c] = acc;
    float s = acc * ats[c], d = acc * atd[c];
#pragma unroll
    for (int off = 1; off < 16; off <<= 1) {
        s += __shfl_xor(s, off);
        d += __shfl_xor(d, off);
    }
    if (c == 0) { as_o[r0 + r] = s; ad_o[r0 + r] = d; }
}

// ---------------- GAT layer 2 aggregation: single pass, no max; + bias + GELU ----------------
__global__ __launch_bounds__(256) void gat2_agg_kernel(const float* __restrict__ H2, const float* __restrict__ as2,
                                                       const float* __restrict__ ad2, const int* __restrict__ rowptr,
                                                       const int* __restrict__ csr_src, const float* __restrict__ bias2,
                                                       float* __restrict__ out) {
    int n = blockIdx.x * 4 + (threadIdx.x >> 6);
    int lane = threadIdx.x & 63;
    int quarter = lane >> 4;
    int c = lane & 15;
    int start = rowptr[n], end = rowptr[n + 1];
    float adn = ad2[n], asn = as2[n];
    float pself = __expf(lrelu(asn + adn));

    float acc = (quarter == 0) ? pself * H2[(size_t)n * 16 + c] : 0.f;
    float d = 0.f;

    for (int base = start; base < end; base += 64) {
        int i = base + lane;
        int s = 0;
        float p = 0.f;
        if (i < end) {
            s = csr_src[i];
            p = __expf(lrelu(as2[s] + adn));
            d += p;
        }
        int cnt = min(64, end - base);
#pragma unroll 2
        for (int j = 0; j < cnt; j += 4) {
            int jj = j + quarter;
            int s0 = __shfl(s, jj);
            float q = __shfl(p, jj);
            if (jj < cnt) acc += q * H2[(size_t)s0 * 16 + c];
        }
    }
#pragma unroll
    for (int off = 1; off < 64; off <<= 1) d += __shfl_xor(d, off);
    float den = d + pself;
    acc += __shfl_xor(acc, 16);
    acc += __shfl_xor(acc, 32);

    if (quarter == 0) {
        float xo = acc / den + bias2[c];
        float t = tanhf(0.7978845608028654f * (xo + 0.044715f * xo * xo * xo));
        out[(size_t)n * 16 + c] = 0.5f * xo * (1.f + t);
    }
}

// ---------------- mean pool per graph + log_softmax ----------------
__global__ __launch_bounds__(256) void pool_lsm_kernel(const float* __restrict__ X, const int* __restrict__ batch,
                                                       int nn, float* __restrict__ out) {
    int g = blockIdx.x;
    int tid = threadIdx.x;
    int lo = 0, hi = nn;
    while (lo < hi) { int mid = (lo + hi) >> 1; if (batch[mid] < g) lo = mid + 1; else hi = mid; }
    int s = lo;
    lo = s; hi = nn;
    while (lo < hi) { int mid = (lo + hi) >> 1; if (batch[mid] < g + 1) lo = mid + 1; else hi = mid; }
    int e2 = lo;
    int c = tid & 15, grp = tid >> 4;
    float acc = 0.f;
    for (int r = s + grp; r < e2; r += 16) acc += X[(size_t)r * 16 + c];
    __shared__ float sm[256];
    sm[tid] = acc;
    __syncthreads();
    for (int off = 8; off >= 1; off >>= 1) {
        if (grp < off) sm[tid] += sm[tid + off * 16];
        __syncthreads();
    }
    if (tid < 16) {
        float cnt = (float)(e2 - s);
        float v = sm[tid] / fmaxf(cnt, 1.f);
        float mx = v;
        mx = fmaxf(mx, __shfl_xor(mx, 1));
        mx = fmaxf(mx, __shfl_xor(mx, 2));
        mx = fmaxf(mx, __shfl_xor(mx, 4));
        mx = fmaxf(mx, __shfl_xor(mx, 8));
        float ex = __expf(v - mx);
        float ssum = ex;
        ssum += __shfl_xor(ssum, 1);
        ssum += __shfl_xor(ssum, 2);
        ssum += __shfl_xor(ssum, 4);
        ssum += __shfl_xor(ssum, 8);
        out[g * 16 + tid] = v - mx - __logf(ssum);
    }
}

extern "C" void kernel_launch(void* const* d_in, const int* in_sizes, int n_in,
                              void* d_out, int out_size, void* d_ws, size_t ws_size,
                              hipStream_t stream) {
    const float* x        = (const float*)d_in[0];
    const float* W1       = (const float*)d_in[1];
    const float* att_src1 = (const float*)d_in[2];
    const float* att_dst1 = (const float*)d_in[3];
    const float* bias1    = (const float*)d_in[4];
    const float* W2       = (const float*)d_in[5];
    const float* att_src2 = (const float*)d_in[6];
    const float* att_dst2 = (const float*)d_in[7];
    const float* bias2    = (const float*)d_in[8];
    const float* bn1g     = (const float*)d_in[9];
    const float* bn1b     = (const float*)d_in[10];
    const float* bn2g     = (const float*)d_in[11];
    const float* bn2b     = (const float*)d_in[12];
    const int*   ei       = (const int*)d_in[13];
    const int*   batch    = (const int*)d_in[14];
    float* out = (float*)d_out;

    char* p = (char*)d_ws;
    auto alloc = [&](size_t bytes) -> char* {
        char* r = p;
        p += (bytes + 255) & ~(size_t)255;
        return r;
    };
    float* bnbuf   = (float*)alloc(512 * sizeof(float));
    int*   deg     = (int*)alloc(NN * sizeof(int));  // contiguous with bnbuf (zero region)
    int*   rowptr  = (int*)alloc((NN + 1) * sizeof(int));
    int*   bcur    = (int*)alloc(NBUCK * sizeof(int));
    int*   csr_src = (int*)alloc(NE * sizeof(int));
    int2*  ebuf    = (int2*)alloc((size_t)NE * sizeof(int2));
    int*   blocksum= (int*)alloc(NBLK * sizeof(int));
    int*   blockoff= (int*)alloc(NBLK * sizeof(int));
    u16*   W1pT    = (u16*)alloc(128 * 128 * sizeof(u16));   // bf16 W1 (BN-folded, transposed)
    float* h1bias  = (float*)alloc(128 * sizeof(float));
    u16*   h1b     = (u16*)alloc((size_t)NN * 128 * sizeof(u16));   // bf16 H1
    float* as1     = (float*)alloc((size_t)NN * 4 * sizeof(float));
    float* ad1     = (float*)alloc((size_t)NN * 4 * sizeof(float));
    float* out1    = (float*)alloc((size_t)NN * 128 * sizeof(float));
    float* W2p     = (float*)alloc(128 * 16 * sizeof(float));
    float* h2bias  = (float*)alloc(16 * sizeof(float));
    float* h2      = (float*)alloc((size_t)NN * 16 * sizeof(float));
    float* as2     = (float*)alloc(NN * sizeof(float));
    float* ad2     = (float*)alloc(NN * sizeof(float));
    float* out2g   = (float*)alloc((size_t)NN * 16 * sizeof(float));

    float* bn1sum = bnbuf;
    float* bn1ss  = bnbuf + 128;
    float* bn2sum = bnbuf + 256;
    float* bn2ss  = bnbuf + 384;
    const int* esrc = ei;
    const int* edst = ei + NE;

    hipMemsetAsync(bnbuf, 0, 512 * sizeof(float) + NN * sizeof(int), stream);

    const float inv_n = 1.f / (float)NN;

    col_stats_kernel<<<256, 256, 0, stream>>>(x, NN, bn1sum, bn1ss);
    bn_prep1_kernel<<<1, 128, 0, stream>>>(bn1sum, bn1ss, bn1g, bn1b, W1, inv_n, W1pT, h1bias);
    gemm1_mfma_kernel<<<(NN + 63) / 64, 256, 0, stream>>>(x, W1pT, h1bias, att_src1, att_dst1, h1b, as1, ad1);
    deg_hist_kernel<<<(NE + 255) / 256, 256, 0, stream>>>(edst, deg, NE);
    scan_part_kernel<<<NBLK, 256, 0, stream>>>(deg, blocksum);
    scan_block_kernel<<<1, 256, 0, stream>>>(blocksum, blockoff);
    scan_final_kernel<<<NBLK, 256, 0, stream>>>(deg, blockoff, rowptr, bcur);
    partition_kernel<<<256, 256, 0, stream>>>(esrc, edst, bcur, ebuf);
    fine_scatter_kernel<<<NBUCK, 256, 0, stream>>>(ebuf, rowptr, csr_src);
    gat1_agg_kernel<<<NN / 4, 256, 0, stream>>>(h1b, as1, ad1, rowptr, csr_src, bias1, out1);
    col_stats_kernel<<<256, 256, 0, stream>>>(out1, NN, bn2sum, bn2ss);
    bn_prep_kernel<<<1, 128, 0, stream>>>(bn2sum, bn2ss, bn2g, bn2b, W2, 16, inv_n, W2p, h2bias);
    gemm2_kernel<<<NN / 16, 256, 0, stream>>>(out1, W2p, h2bias, att_src2, att_dst2, h2, as2, ad2);
    gat2_agg_kernel<<<NN / 4, 256, 0, stream>>>(h2, as2, ad2, rowptr, csr_src, bias2, out2g);
    pool_lsm_kernel<<<NG, 256, 0, stream>>>(out2g, batch, NN, out);
}

// Round 9
// 308.368 us; speedup vs baseline: 1.9045x; 1.1411x over previous
//
#include <hip/hip_runtime.h>
#include <math.h>
#include <stdint.h>

#define NN 50000
#define NE 800000
#define NG 64
#define NEG_SLOPE 0.2f
#define BSH 8
#define NBUCK ((NN + 255) >> 8)   // 196 dst-buckets (256 nodes each)

typedef unsigned short u16;
typedef __attribute__((ext_vector_type(8))) unsigned short ushort8;
typedef __attribute__((ext_vector_type(8))) short short8v;   // MFMA bf16 A/B frag (4 VGPRs)
typedef __attribute__((ext_vector_type(4))) float f32x4;     // MFMA C/D frag

__device__ __forceinline__ float lrelu(float x) { return x > 0.f ? x : NEG_SLOPE * x; }
__device__ __forceinline__ float bf2f(u16 u) { return __uint_as_float(((unsigned)u) << 16); }
__device__ __forceinline__ u16 f2bf(float f) {
    unsigned b = __float_as_uint(f);
    return (u16)((b + 0x7FFF + ((b >> 16) & 1)) >> 16);  // RNE
}

// ---------------- column stats fp32 input ----------------
__global__ __launch_bounds__(256) void col_stats_kernel(const float* __restrict__ X, int nrows,
                                                        float* __restrict__ sum, float* __restrict__ ssum) {
    int tid = threadIdx.x;
    int c = tid & 127, half = tid >> 7;
    int rows_per = (nrows + gridDim.x - 1) / gridDim.x;
    int r0 = blockIdx.x * rows_per;
    int r1 = r0 + rows_per; if (r1 > nrows) r1 = nrows;
    float s = 0.f, ss = 0.f;
    for (int r = r0 + half; r < r1; r += 2) {
        float v = X[(size_t)r * 128 + c];
        s += v; ss += v * v;
    }
    __shared__ float sm1[256], sm2[256];
    sm1[tid] = s; sm2[tid] = ss;
    __syncthreads();
    if (tid < 128) {
        s = sm1[tid] + sm1[tid + 128];
        ss = sm2[tid] + sm2[tid + 128];
        atomicAdd(&sum[c], s);
        atomicAdd(&ssum[c], ss);
    }
}

// ---------------- column stats bf16 input ----------------
__global__ __launch_bounds__(256) void col_stats_bf16_kernel(const u16* __restrict__ X, int nrows,
                                                             float* __restrict__ sum, float* __restrict__ ssum) {
    int tid = threadIdx.x;
    int c = tid & 127, half = tid >> 7;
    int rows_per = (nrows + gridDim.x - 1) / gridDim.x;
    int r0 = blockIdx.x * rows_per;
    int r1 = r0 + rows_per; if (r1 > nrows) r1 = nrows;
    float s = 0.f, ss = 0.f;
    for (int r = r0 + half; r < r1; r += 2) {
        float v = bf2f(X[(size_t)r * 128 + c]);
        s += v; ss += v * v;
    }
    __shared__ float sm1[256], sm2[256];
    sm1[tid] = s; sm2[tid] = ss;
    __syncthreads();
    if (tid < 128) {
        s = sm1[tid] + sm1[tid + 128];
        ss = sm2[tid] + sm2[tid + 128];
        atomicAdd(&sum[c], s);
        atomicAdd(&ssum[c], ss);
    }
}

// ---------------- BN fold layer1: W1pT[j][k] = bf16(a_k*W[k][j]); hbias fp32 ----------------
__global__ __launch_bounds__(128) void bn_prep1_kernel(const float* __restrict__ sum, const float* __restrict__ ssum,
                                                       const float* __restrict__ gamma, const float* __restrict__ beta,
                                                       const float* __restrict__ W, float inv_n,
                                                       u16* __restrict__ WpT, float* __restrict__ hb) {
    int k = threadIdx.x; // 128
    float mean = sum[k] * inv_n;
    float var = ssum[k] * inv_n - mean * mean;
    float a = gamma[k] * rsqrtf(var + 1e-5f);
    float b = beta[k] - mean * a;
    for (int j = 0; j < 128; j++) WpT[j * 128 + k] = f2bf(a * W[k * 128 + j]);
    __shared__ float bs[128];
    bs[k] = b;
    __syncthreads();
    float acc = 0.f;
    for (int kk = 0; kk < 128; kk++) acc += bs[kk] * W[kk * 128 + k];
    hb[k] = acc;
}

// ---------------- BN fold layer2: W2pT[j][k] (bf16, 16x128) + h2bias ----------------
__global__ __launch_bounds__(128) void bn_prep2_kernel(const float* __restrict__ sum, const float* __restrict__ ssum,
                                                       const float* __restrict__ gamma, const float* __restrict__ beta,
                                                       const float* __restrict__ W, float inv_n,
                                                       u16* __restrict__ WpT, float* __restrict__ hb) {
    int k = threadIdx.x; // 128
    float mean = sum[k] * inv_n;
    float var = ssum[k] * inv_n - mean * mean;
    float a = gamma[k] * rsqrtf(var + 1e-5f);
    float b = beta[k] - mean * a;
    for (int j = 0; j < 16; j++) WpT[j * 128 + k] = f2bf(a * W[k * 16 + j]);
    __shared__ float bs[128];
    bs[k] = b;
    __syncthreads();
    if (k < 16) {
        float acc = 0.f;
        for (int kk = 0; kk < 128; kk++) acc += bs[kk] * W[kk * 16 + k];
        hb[k] = acc;
    }
}

// ---------------- GEMM1 via MFMA bf16: Hb = bf16(X @ W1p) + fused as1/ad1 epilogue ----------------
__global__ __launch_bounds__(256) void gemm1_mfma_kernel(const float* __restrict__ X, const u16* __restrict__ WpT,
                                                         const float* __restrict__ hbias, const float* __restrict__ atts,
                                                         const float* __restrict__ attd, u16* __restrict__ Hb,
                                                         float* __restrict__ as_o, float* __restrict__ ad_o) {
    __shared__ u16 wlds[128][136];   // [col][k], padded pitch
    int tid = threadIdx.x;
    for (int u = tid; u < 2048; u += 256) {    // 128 cols x 16 chunks of 8 u16
        int c = u >> 4, ch = u & 15;
        *(ushort8*)&wlds[c][ch * 8] = *(const ushort8*)&WpT[c * 128 + ch * 8];
    }
    int lane = tid & 63;
    int wv = tid >> 6;
    int cl = lane & 15;
    int kg = lane >> 4;
    int row_base = blockIdx.x * 64 + wv * 16;
    int rr = min(row_base + cl, NN - 1);       // A row (clamped; invalid rows discarded at store)

    short8v afrag[4];
#pragma unroll
    for (int kb = 0; kb < 4; kb++) {
        const float* xp = &X[(size_t)rr * 128 + kb * 32 + kg * 8];
        float4 x0 = *(const float4*)xp;
        float4 x1 = *(const float4*)(xp + 4);
        ushort8 t;
        t[0] = f2bf(x0.x); t[1] = f2bf(x0.y); t[2] = f2bf(x0.z); t[3] = f2bf(x0.w);
        t[4] = f2bf(x1.x); t[5] = f2bf(x1.y); t[6] = f2bf(x1.z); t[7] = f2bf(x1.w);
        afrag[kb] = (short8v)t;
    }
    __syncthreads();

    f32x4 acc[8];
#pragma unroll
    for (int ct = 0; ct < 8; ct++) {
        f32x4 a = {0.f, 0.f, 0.f, 0.f};
#pragma unroll
        for (int kb = 0; kb < 4; kb++) {
            ushort8 bv = *(const ushort8*)&wlds[ct * 16 + cl][kb * 32 + kg * 8];
            a = __builtin_amdgcn_mfma_f32_16x16x32_bf16(afrag[kb], (short8v)bv, a, 0, 0, 0);
        }
        acc[ct] = a;
    }

    // epilogue: +hbias, bf16 store, fused as1/ad1 (per-head dot + 16-lane reduce)
#pragma unroll
    for (int reg = 0; reg < 4; reg++) {
        int r = row_base + kg * 4 + reg;       // C/D row mapping (m89)
        bool valid = (r < NN);
        float sp[4] = {0.f, 0.f, 0.f, 0.f}, dp[4] = {0.f, 0.f, 0.f, 0.f};
#pragma unroll
        for (int ct = 0; ct < 8; ct++) {
            int c = ct * 16 + cl;
            float v = acc[ct][reg] + hbias[c];
            if (valid) Hb[(size_t)r * 128 + c] = f2bf(v);
            sp[ct >> 1] += v * atts[c];
            dp[ct >> 1] += v * attd[c];
        }
#pragma unroll
        for (int off = 1; off < 16; off <<= 1) {
#pragma unroll
            for (int h = 0; h < 4; h++) {
                sp[h] += __shfl_xor(sp[h], off);
                dp[h] += __shfl_xor(dp[h], off);
            }
        }
        if (valid) {
            if (cl < 4) as_o[r * 4 + cl] = sp[cl];
            else if (cl < 8) ad_o[r * 4 + (cl - 4)] = dp[cl - 4];
        }
    }
}

// ---------------- CSR build: bucket counts -> scan196 -> partition -> fine scatter ----------------
__global__ __launch_bounds__(256) void bucket_count_kernel(const int* __restrict__ edst, int* __restrict__ bucket_cnt) {
    __shared__ int hist[NBUCK];
    int tid = threadIdx.x;
    for (int b = tid; b < NBUCK; b += 256) hist[b] = 0;
    __syncthreads();
    int epb = (NE + gridDim.x - 1) / gridDim.x;
    int e0 = blockIdx.x * epb;
    int e1 = min(e0 + epb, NE);
    for (int e = e0 + tid; e < e1; e += 256) atomicAdd(&hist[edst[e] >> BSH], 1);
    __syncthreads();
    for (int b = tid; b < NBUCK; b += 256) if (hist[b]) atomicAdd(&bucket_cnt[b], hist[b]);
}

__global__ __launch_bounds__(256) void scan196_kernel(const int* __restrict__ bucket_cnt,
                                                      int* __restrict__ bucket_base, int* __restrict__ bcur) {
    __shared__ int sm[256];
    int tid = threadIdx.x;
    int v = (tid < NBUCK) ? bucket_cnt[tid] : 0;
    sm[tid] = v;
    __syncthreads();
    for (int off = 1; off < 256; off <<= 1) {
        int t = (tid >= off) ? sm[tid - off] : 0;
        __syncthreads();
        sm[tid] += t;
        __syncthreads();
    }
    if (tid < NBUCK) {
        int ex = sm[tid] - v;
        bucket_base[tid] = ex;
        bcur[tid] = ex;
    }
    if (tid == NBUCK - 1) bucket_base[NBUCK] = sm[tid];
}

__global__ __launch_bounds__(256) void partition_kernel(const int* __restrict__ esrc, const int* __restrict__ edst,
                                                        int* __restrict__ bcur, int2* __restrict__ ebuf) {
    __shared__ int hist[NBUCK];
    __shared__ int cur[NBUCK];
    int tid = threadIdx.x;
    for (int b = tid; b < NBUCK; b += 256) hist[b] = 0;
    __syncthreads();
    int epb = (NE + gridDim.x - 1) / gridDim.x;
    int e0 = blockIdx.x * epb;
    int e1 = min(e0 + epb, NE);
    for (int e = e0 + tid; e < e1; e += 256)
        atomicAdd(&hist[edst[e] >> BSH], 1);
    __syncthreads();
    for (int b = tid; b < NBUCK; b += 256) {
        int h = hist[b];
        cur[b] = h ? atomicAdd(&bcur[b], h) : 0;
    }
    __syncthreads();
    for (int e = e0 + tid; e < e1; e += 256) {
        int s = esrc[e], d = edst[e];
        int pos = atomicAdd(&cur[d >> BSH], 1);
        ebuf[pos] = make_int2(s, d);
    }
}

// per bucket: LDS deg count + scan -> rowptr; LDS cursors -> csr_src scatter
__global__ __launch_bounds__(256) void fine_scatter_kernel(const int2* __restrict__ ebuf,
                                                           const int* __restrict__ bucket_base,
                                                           int* __restrict__ rowptr, int* __restrict__ csr_src) {
    __shared__ int ldeg[256];
    __shared__ int ssc[256];
    __shared__ int lcur[256];
    int b = blockIdx.x, tid = threadIdx.x;
    int n0 = b << BSH;
    int e0 = bucket_base[b], e1 = bucket_base[b + 1];
    ldeg[tid] = 0;
    __syncthreads();
    for (int e = e0 + tid; e < e1; e += 256) atomicAdd(&ldeg[ebuf[e].y - n0], 1);
    __syncthreads();
    int d = ldeg[tid];
    ssc[tid] = d;
    __syncthreads();
    for (int off = 1; off < 256; off <<= 1) {
        int t = (tid >= off) ? ssc[tid - off] : 0;
        __syncthreads();
        ssc[tid] += t;
        __syncthreads();
    }
    int excl = e0 + ssc[tid] - d;
    int n = n0 + tid;
    if (n < NN) rowptr[n] = excl;
    lcur[tid] = excl;
    if (b == NBUCK - 1 && tid == 0) rowptr[NN] = e1;
    __syncthreads();
    for (int e = e0 + tid; e < e1; e += 256) {
        int2 p = ebuf[e];
        int pos = atomicAdd(&lcur[p.y - n0], 1);
        csr_src[pos] = p.x;
    }
}

// ---------------- GAT layer 1 aggregation: single pass, no max, bf16 in/out ----------------
__global__ __launch_bounds__(256) void gat1_agg_kernel(const u16* __restrict__ Hb, const float* __restrict__ as1,
                                                       const float* __restrict__ ad1, const int* __restrict__ rowptr,
                                                       const int* __restrict__ csr_src, const float* __restrict__ bias1,
                                                       u16* __restrict__ out) {
    int n = blockIdx.x * 4 + (threadIdx.x >> 6);
    int lane = threadIdx.x & 63;
    int quarter = lane >> 4;   // which edge of the in-flight quad
    int within = lane & 15;    // channel group: [within*8, within*8+8)
    int head = within >> 2;    // head of these channels
    int c8 = within * 8;
    int start = rowptr[n], end = rowptr[n + 1];

    float4 ad4 = *(const float4*)&ad1[n * 4];
    float4 as4 = *(const float4*)&as1[n * 4];
    float ps0 = __expf(lrelu(as4.x + ad4.x));
    float ps1 = __expf(lrelu(as4.y + ad4.y));
    float ps2 = __expf(lrelu(as4.z + ad4.z));
    float ps3 = __expf(lrelu(as4.w + ad4.w));
    float pselfh = (head == 0) ? ps0 : (head == 1) ? ps1 : (head == 2) ? ps2 : ps3;

    float acc[8];
    {   // self-loop contribution (quarter 0 only; folded later)
        ushort8 hv = *(const ushort8*)&Hb[(size_t)n * 128 + c8];
        float w = (quarter == 0) ? pselfh : 0.f;
#pragma unroll
        for (int k = 0; k < 8; k++) acc[k] = w * bf2f(hv[k]);
    }
    float d0 = 0.f, d1 = 0.f, d2 = 0.f, d3 = 0.f;

    for (int base = start; base < end; base += 64) {
        int i = base + lane;
        int s = 0;
        float p0 = 0.f, p1 = 0.f, p2 = 0.f, p3 = 0.f;
        if (i < end) {
            s = csr_src[i];
            float4 a = *(const float4*)&as1[(size_t)s * 4];
            p0 = __expf(lrelu(a.x + ad4.x));
            p1 = __expf(lrelu(a.y + ad4.y));
            p2 = __expf(lrelu(a.z + ad4.z));
            p3 = __expf(lrelu(a.w + ad4.w));
            d0 += p0; d1 += p1; d2 += p2; d3 += p3;
        }
        int cnt = min(64, end - base);
#pragma unroll 2
        for (int j = 0; j < cnt; j += 4) {
            int jj = j + quarter;
            int s0 = __shfl(s, jj);
            float q0 = __shfl(p0, jj);
            float q1 = __shfl(p1, jj);
            float q2 = __shfl(p2, jj);
            float q3 = __shfl(p3, jj);
            float pp = (head == 0) ? q0 : (head == 1) ? q1 : (head == 2) ? q2 : q3;
            if (jj < cnt) {
                ushort8 hv = *(const ushort8*)&Hb[(size_t)s0 * 128 + c8];
#pragma unroll
                for (int k = 0; k < 8; k++) acc[k] += pp * bf2f(hv[k]);
            }
        }
    }

#pragma unroll
    for (int off = 1; off < 64; off <<= 1) {
        d0 += __shfl_xor(d0, off);
        d1 += __shfl_xor(d1, off);
        d2 += __shfl_xor(d2, off);
        d3 += __shfl_xor(d3, off);
    }
    float den = ((head == 0) ? d0 : (head == 1) ? d1 : (head == 2) ? d2 : d3) + pselfh;
#pragma unroll
    for (int k = 0; k < 8; k++) {
        acc[k] += __shfl_xor(acc[k], 16);
        acc[k] += __shfl_xor(acc[k], 32);
    }
    if (quarter == 0) {
        float inv = 1.f / den;
        float4 b0 = *(const float4*)&bias1[c8];
        float4 b1 = *(const float4*)&bias1[c8 + 4];
        ushort8 o;
        o[0] = f2bf(fmaxf(acc[0] * inv + b0.x, 0.f));
        o[1] = f2bf(fmaxf(acc[1] * inv + b0.y, 0.f));
        o[2] = f2bf(fmaxf(acc[2] * inv + b0.z, 0.f));
        o[3] = f2bf(fmaxf(acc[3] * inv + b0.w, 0.f));
        o[4] = f2bf(fmaxf(acc[4] * inv + b1.x, 0.f));
        o[5] = f2bf(fmaxf(acc[5] * inv + b1.y, 0.f));
        o[6] = f2bf(fmaxf(acc[6] * inv + b1.z, 0.f));
        o[7] = f2bf(fmaxf(acc[7] * inv + b1.w, 0.f));
        *(ushort8*)&out[(size_t)n * 128 + c8] = o;
    }
}

// ---------------- GEMM2 via MFMA bf16: H2[N,16] = out1b @ W2p + fused as2/ad2 ----------------
// Block = 4 waves x 16 rows = 64 rows; per wave 4 MFMAs (1 col-tile x 4 K-blocks); A direct from bf16.
__global__ __launch_bounds__(256) void gemm2_mfma_kernel(const u16* __restrict__ Xb, const u16* __restrict__ W2pT,
                                                         const float* __restrict__ hb, const float* __restrict__ atts,
                                                         const float* __restrict__ attd, float* __restrict__ H2,
                                                         float* __restrict__ as_o, float* __restrict__ ad_o) {
    __shared__ u16 wlds[16][136];
    int tid = threadIdx.x;
    {
        int c = tid >> 4, ch = tid & 15;
        *(ushort8*)&wlds[c][ch * 8] = *(const ushort8*)&W2pT[c * 128 + ch * 8];
    }
    int lane = tid & 63, wv = tid >> 6;
    int cl = lane & 15, kg = lane >> 4;
    int row_base = blockIdx.x * 64 + wv * 16;
    int rr = min(row_base + cl, NN - 1);
    __syncthreads();

    f32x4 a = {0.f, 0.f, 0.f, 0.f};
#pragma unroll
    for (int kb = 0; kb < 4; kb++) {
        ushort8 av = *(const ushort8*)&Xb[(size_t)rr * 128 + kb * 32 + kg * 8];
        ushort8 bv = *(const ushort8*)&wlds[cl][kb * 32 + kg * 8];
        a = __builtin_amdgcn_mfma_f32_16x16x32_bf16((short8v)av, (short8v)bv, a, 0, 0, 0);
    }
    float ats = atts[cl], atd = attd[cl], hbc = hb[cl];
#pragma unroll
    for (int reg = 0; reg < 4; reg++) {
        int r = row_base + kg * 4 + reg;
        bool valid = (r < NN);
        float v = a[reg] + hbc;
        if (valid) H2[(size_t)r * 16 + cl] = v;
        float s = v * ats, d = v * atd;
#pragma unroll
        for (int off = 1; off < 16; off <<= 1) {
            s += __shfl_xor(s, off);
            d += __shfl_xor(d, off);
        }
        if (valid) {
            if (cl == 0) as_o[r] = s;
            else if (cl == 1) ad_o[r] = d;
        }
    }
}

// ---------------- GAT layer 2 aggregation: single pass, no max; + bias + GELU ----------------
__global__ __launch_bounds__(256) void gat2_agg_kernel(const float* __restrict__ H2, const float* __restrict__ as2,
                                                       const float* __restrict__ ad2, const int* __restrict__ rowptr,
                                                       const int* __restrict__ csr_src, const float* __restrict__ bias2,
                                                       float* __restrict__ out) {
    int n = blockIdx.x * 4 + (threadIdx.x >> 6);
    int lane = threadIdx.x & 63;
    int quarter = lane >> 4;
    int c = lane & 15;
    int start = rowptr[n], end = rowptr[n + 1];
    float adn = ad2[n], asn = as2[n];
    float pself = __expf(lrelu(asn + adn));

    float acc = (quarter == 0) ? pself * H2[(size_t)n * 16 + c] : 0.f;
    float d = 0.f;

    for (int base = start; base < end; base += 64) {
        int i = base + lane;
        int s = 0;
        float p = 0.f;
        if (i < end) {
            s = csr_src[i];
            p = __expf(lrelu(as2[s] + adn));
            d += p;
        }
        int cnt = min(64, end - base);
#pragma unroll 2
        for (int j = 0; j < cnt; j += 4) {
            int jj = j + quarter;
            int s0 = __shfl(s, jj);
            float q = __shfl(p, jj);
            if (jj < cnt) acc += q * H2[(size_t)s0 * 16 + c];
        }
    }
#pragma unroll
    for (int off = 1; off < 64; off <<= 1) d += __shfl_xor(d, off);
    float den = d + pself;
    acc += __shfl_xor(acc, 16);
    acc += __shfl_xor(acc, 32);

    if (quarter == 0) {
        float xo = acc / den + bias2[c];
        float t = tanhf(0.7978845608028654f * (xo + 0.044715f * xo * xo * xo));
        out[(size_t)n * 16 + c] = 0.5f * xo * (1.f + t);
    }
}

// ---------------- mean pool per graph + log_softmax ----------------
__global__ __launch_bounds__(256) void pool_lsm_kernel(const float* __restrict__ X, const int* __restrict__ batch,
                                                       int nn, float* __restrict__ out) {
    int g = blockIdx.x;
    int tid = threadIdx.x;
    int lo = 0, hi = nn;
    while (lo < hi) { int mid = (lo + hi) >> 1; if (batch[mid] < g) lo = mid + 1; else hi = mid; }
    int s = lo;
    lo = s; hi = nn;
    while (lo < hi) { int mid = (lo + hi) >> 1; if (batch[mid] < g + 1) lo = mid + 1; else hi = mid; }
    int e2 = lo;
    int c = tid & 15, grp = tid >> 4;
    float acc = 0.f;
    for (int r = s + grp; r < e2; r += 16) acc += X[(size_t)r * 16 + c];
    __shared__ float sm[256];
    sm[tid] = acc;
    __syncthreads();
    for (int off = 8; off >= 1; off >>= 1) {
        if (grp < off) sm[tid] += sm[tid + off * 16];
        __syncthreads();
    }
    if (tid < 16) {
        float cnt = (float)(e2 - s);
        float v = sm[tid] / fmaxf(cnt, 1.f);
        float mx = v;
        mx = fmaxf(mx, __shfl_xor(mx, 1));
        mx = fmaxf(mx, __shfl_xor(mx, 2));
        mx = fmaxf(mx, __shfl_xor(mx, 4));
        mx = fmaxf(mx, __shfl_xor(mx, 8));
        float ex = __expf(v - mx);
        float ssum = ex;
        ssum += __shfl_xor(ssum, 1);
        ssum += __shfl_xor(ssum, 2);
        ssum += __shfl_xor(ssum, 4);
        ssum += __shfl_xor(ssum, 8);
        out[g * 16 + tid] = v - mx - __logf(ssum);
    }
}

extern "C" void kernel_launch(void* const* d_in, const int* in_sizes, int n_in,
                              void* d_out, int out_size, void* d_ws, size_t ws_size,
                              hipStream_t stream) {
    const float* x        = (const float*)d_in[0];
    const float* W1       = (const float*)d_in[1];
    const float* att_src1 = (const float*)d_in[2];
    const float* att_dst1 = (const float*)d_in[3];
    const float* bias1    = (const float*)d_in[4];
    const float* W2       = (const float*)d_in[5];
    const float* att_src2 = (const float*)d_in[6];
    const float* att_dst2 = (const float*)d_in[7];
    const float* bias2    = (const float*)d_in[8];
    const float* bn1g     = (const float*)d_in[9];
    const float* bn1b     = (const float*)d_in[10];
    const float* bn2g     = (const float*)d_in[11];
    const float* bn2b     = (const float*)d_in[12];
    const int*   ei       = (const int*)d_in[13];
    const int*   batch    = (const int*)d_in[14];
    float* out = (float*)d_out;

    char* p = (char*)d_ws;
    auto alloc = [&](size_t bytes) -> char* {
        char* r = p;
        p += (bytes + 255) & ~(size_t)255;
        return r;
    };
    float* bnbuf      = (float*)alloc(512 * sizeof(float));     // bn1sum|bn1ss|bn2sum|bn2ss (2048B, 256-aligned)
    int*   bucket_cnt = (int*)alloc(NBUCK * sizeof(int));       // contiguous with bnbuf -> single memset
    int*   bucket_base= (int*)alloc((NBUCK + 1) * sizeof(int));
    int*   bcur       = (int*)alloc(NBUCK * sizeof(int));
    int*   rowptr     = (int*)alloc((NN + 1) * sizeof(int));
    int*   csr_src    = (int*)alloc(NE * sizeof(int));
    int2*  ebuf       = (int2*)alloc((size_t)NE * sizeof(int2));
    u16*   W1pT       = (u16*)alloc(128 * 128 * sizeof(u16));   // bf16 W1 (BN-folded, transposed)
    float* h1bias     = (float*)alloc(128 * sizeof(float));
    u16*   h1b        = (u16*)alloc((size_t)NN * 128 * sizeof(u16));   // bf16 H1
    float* as1        = (float*)alloc((size_t)NN * 4 * sizeof(float));
    float* ad1        = (float*)alloc((size_t)NN * 4 * sizeof(float));
    u16*   out1b      = (u16*)alloc((size_t)NN * 128 * sizeof(u16));   // bf16 layer-1 output
    u16*   W2pT       = (u16*)alloc(16 * 128 * sizeof(u16));
    float* h2bias     = (float*)alloc(16 * sizeof(float));
    float* h2         = (float*)alloc((size_t)NN * 16 * sizeof(float));
    float* as2        = (float*)alloc(NN * sizeof(float));
    float* ad2        = (float*)alloc(NN * sizeof(float));
    float* out2g      = (float*)alloc((size_t)NN * 16 * sizeof(float));

    float* bn1sum = bnbuf;
    float* bn1ss  = bnbuf + 128;
    float* bn2sum = bnbuf + 256;
    float* bn2ss  = bnbuf + 384;
    const int* esrc = ei;
    const int* edst = ei + NE;

    // zero: bn stats (2048B) + bucket_cnt (784B) contiguous
    hipMemsetAsync(bnbuf, 0, 512 * sizeof(float) + NBUCK * sizeof(int), stream);

    const float inv_n = 1.f / (float)NN;

    col_stats_kernel<<<256, 256, 0, stream>>>(x, NN, bn1sum, bn1ss);
    bn_prep1_kernel<<<1, 128, 0, stream>>>(bn1sum, bn1ss, bn1g, bn1b, W1, inv_n, W1pT, h1bias);
    gemm1_mfma_kernel<<<(NN + 63) / 64, 256, 0, stream>>>(x, W1pT, h1bias, att_src1, att_dst1, h1b, as1, ad1);
    bucket_count_kernel<<<256, 256, 0, stream>>>(edst, bucket_cnt);
    scan196_kernel<<<1, 256, 0, stream>>>(bucket_cnt, bucket_base, bcur);
    partition_kernel<<<256, 256, 0, stream>>>(esrc, edst, bcur, ebuf);
    fine_scatter_kernel<<<NBUCK, 256, 0, stream>>>(ebuf, bucket_base, rowptr, csr_src);
    gat1_agg_kernel<<<NN / 4, 256, 0, stream>>>(h1b, as1, ad1, rowptr, csr_src, bias1, out1b);
    col_stats_bf16_kernel<<<256, 256, 0, stream>>>(out1b, NN, bn2sum, bn2ss);
    bn_prep2_kernel<<<1, 128, 0, stream>>>(bn2sum, bn2ss, bn2g, bn2b, W2, inv_n, W2pT, h2bias);
    gemm2_mfma_kernel<<<(NN + 63) / 64, 256, 0, stream>>>(out1b, W2pT, h2bias, att_src2, att_dst2, h2, as2, ad2);
    gat2_agg_kernel<<<NN / 4, 256, 0, stream>>>(h2, as2, ad2, rowptr, csr_src, bias2, out2g);
    pool_lsm_kernel<<<NG, 256, 0, stream>>>(out2g, batch, NN, out);
}